// Round 2
// baseline (1190.210 us; speedup 1.0000x reference)
//
#include <hip/hip_runtime.h>
#include <hip/hip_bf16.h>

#define NT 1024
#define NNODES 4096
#define ECAP 65536   // max arcs after iteration-1 symmetrization (E0 <= 32768)

// ---------------- grid-parallel 2MB bitmap zero (replaces hipMemsetAsync) ----------------
__global__ __launch_bounds__(256)
void zeroBM(int4* __restrict__ bm) {
    bm[(size_t)blockIdx.x * 256 + threadIdx.x] = make_int4(0, 0, 0, 0);
}

// ---------------- block-wide exclusive scan over NT=1024 values ----------------
__device__ __forceinline__ int blockScanExcl(int v, int* s_w, int* total) {
    const int tid  = threadIdx.x;
    const int lane = tid & 63;
    const int wv   = tid >> 6;
    int x = v;
#pragma unroll
    for (int off = 1; off < 64; off <<= 1) {
        int t = __shfl_up(x, off, 64);
        if (lane >= off) x += t;
    }
    if (lane == 63) s_w[wv] = x;
    __syncthreads();
    if (tid < 16) {
        int y = s_w[tid];
#pragma unroll
        for (int off = 1; off < 16; off <<= 1) {
            int t = __shfl_up(y, off, 16);
            if (tid >= off) y += t;
        }
        s_w[tid] = y;
    }
    __syncthreads();
    int base = wv ? s_w[wv - 1] : 0;
    int tot  = s_w[15];
    __syncthreads();   // protect s_w reuse
    *total = tot;
    return base + x - v;   // exclusive prefix
}

// ================= Phase A1: preamble (R4-exact), dump handoff state =================
// s_bc slots: 0=node 2=nbrCnt 4=orderBase 5=appendBase 7=maxdeg 9=not64
__global__ __launch_bounds__(NT, 1)
void phaseA1(const int* __restrict__ ei, int E0,
             int* __restrict__ U, int* __restrict__ V,
             unsigned int* __restrict__ BM,
             int* __restrict__ NBR, int* __restrict__ OTH,
             int* __restrict__ ORDV, int* __restrict__ ROFFG, int* __restrict__ RENDG,
             int* __restrict__ HAND)
{
    __shared__ unsigned short s_order[NNODES];
    __shared__ unsigned char  s_vis[NNODES];
    __shared__ unsigned char  s_rank[NNODES];     // counting-sort within-group rank
    __shared__ unsigned int   s_hb[NNODES / 32];
    __shared__ int s_roff[NNODES];
    __shared__ int s_rend[NNODES];
    __shared__ int s_tmp[NNODES];
    __shared__ int s_mat[64][65];                 // [deg][group] counts / prefixes; col 64 = desc base
    __shared__ int s_w[16];
    __shared__ int s_bc[16];

    const int tid = threadIdx.x;

    for (int i = tid; i < NNODES; i += NT) { s_vis[i] = 0; s_tmp[i] = 0; }
    for (int i = tid; i < NNODES / 32; i += NT) s_hb[i] = 0;
    if (tid < 16) s_bc[tid] = 0;
    __syncthreads();

    // ---- detect int64 vs int32 edge buffer ----
    for (int i = tid; i < E0; i += NT)
        if (ei[2 * i + 1] != 0) s_bc[9] = 1;
    __syncthreads();
    const int is64 = !s_bc[9];

    // ---- copy edges + degree histogram (I+O) ----
    for (int e = tid; e < E0; e += NT) {
        int uu = ei[is64 ? 2 * e : e];
        int vv = ei[is64 ? 2 * (E0 + e) : (E0 + e)];
        U[e] = uu; V[e] = vv;
        atomicAdd(&s_tmp[uu], 1);
        atomicAdd(&s_tmp[vv], 1);
    }
    __syncthreads();
    for (int n = tid; n < NNODES; n += NT) atomicMax(&s_bc[7], s_tmp[n]);
    __syncthreads();
    const int maxd = s_bc[7];

    // ---- stable argsort by descending degree ----
    if (maxd < 64) {
        // fast path: stable counting sort, ~5 barriers total.
        // position(n) = #{deg > d_n} + #{m<n : deg_m == d_n}; second term split as
        // cross-group prefix (s_mat[d][g]) + within-group ballot rank.
        const int wv = tid >> 6, lane = tid & 63;
        const unsigned long long ltm = (1ull << lane) - 1ull;
        for (int g = wv; g < 64; g += 16) {
            int n = g * 64 + lane;
            int d = s_tmp[n];
            int rk = 0;
            for (int dd = 0; dd < 64; ++dd) {
                unsigned long long bal = __ballot(d == dd);
                if (lane == 0) s_mat[dd][g] = __popcll(bal);
                if (d == dd) rk = __popcll(bal & ltm);
            }
            s_rank[n] = (unsigned char)rk;
        }
        __syncthreads();
        if (tid < 64) {                      // per-degree prefix across the 64 id-groups
            int run = 0;
            for (int g = 0; g < 64; ++g) { int t = s_mat[tid][g]; s_mat[tid][g] = run; run += t; }
            s_mat[tid][64] = run;            // total per degree
        }
        __syncthreads();
        if (tid < 64) {                      // descending-degree exclusive base
            int x = s_mat[tid][64];
#pragma unroll
            for (int off = 1; off < 64; off <<= 1) {
                int t = __shfl_up(x, off, 64);
                if (tid >= off) x += t;
            }
            int T = __shfl(x, 63, 64);
            s_mat[tid][64] = T - x;          // sum of bins with degree > tid
        }
        __syncthreads();
        for (int g = wv; g < 64; g += 16) {
            int n = g * 64 + lane;
            int d = s_tmp[n];
            int pos = s_mat[d][64] + s_mat[d][g] + (int)s_rank[n];
            s_order[pos] = (unsigned short)n;
        }
        __syncthreads();
    } else {
        // legacy fallback (exact, slow): one scan round per degree value
        for (int d = maxd; d >= 0; --d) {
            int n0 = tid * 4;
            int f0 = (s_tmp[n0] == d), f1 = (s_tmp[n0 + 1] == d);
            int f2 = (s_tmp[n0 + 2] == d), f3 = (s_tmp[n0 + 3] == d);
            int tot;
            int off = blockScanExcl(f0 + f1 + f2 + f3, s_w, &tot);
            int idx = s_bc[4] + off;
            if (f0) s_order[idx++] = (unsigned short)n0;
            if (f1) s_order[idx++] = (unsigned short)(n0 + 1);
            if (f2) s_order[idx++] = (unsigned short)(n0 + 2);
            if (f3) s_order[idx++] = (unsigned short)(n0 + 3);
            __syncthreads();
            if (tid == 0) s_bc[4] += tot;
            __syncthreads();
        }
    }

    // ---- iteration 0 (full-array scans, eager relabel) ----
    if (tid == 0) {
        int nd = s_order[0];
        s_bc[0] = nd; s_vis[nd] = 1;
    }
    __syncthreads();
    {
        const int node = s_bc[0];
        for (int e = tid; e < E0; e += NT) {
            int uu = U[e], vv = V[e];
            if (uu == node) {
                int w = vv; unsigned m = 1u << (w & 31);
                unsigned old = atomicOr(&s_hb[w >> 5], m);
                if (!(old & m)) { int i = atomicAdd(&s_bc[2], 1); s_tmp[i] = w; s_vis[w] = 1; }
            }
            if (vv == node) {
                int w = uu; unsigned m = 1u << (w & 31);
                unsigned old = atomicOr(&s_hb[w >> 5], m);
                if (!(old & m)) { int i = atomicAdd(&s_bc[2], 1); s_tmp[i] = w; s_vis[w] = 1; }
            }
        }
        __syncthreads();
        // eager relabel Hn = H \ {node} (U/V frozen afterwards)
        for (int e = tid; e < E0; e += NT) {
            int uu = U[e];
            if (uu != node && ((s_hb[uu >> 5] >> (uu & 31)) & 1)) U[e] = node;
            int vv = V[e];
            if (vv != node && ((s_hb[vv >> 5] >> (vv & 31)) & 1)) V[e] = node;
        }
        __syncthreads();
    }

    // ---- symmetry append (only iteration ever needing it) ----
    // BM is pre-zeroed by the grid-parallel zeroBM kernel on the stream.
    for (int e = tid; e < E0; e += NT) {
        int uu = U[e], vv = V[e];
        if (uu != vv) {
            unsigned code = ((unsigned)uu << 12) | (unsigned)vv;
            atomicOr(&BM[code >> 5], 1u << (code & 31));
        }
    }
    __syncthreads();
    // single-pass ordered compaction: 32 arcs/thread bitmask + one block scan per 32K chunk
    for (int t0 = 0; t0 < E0; t0 += NT * 32) {
        unsigned fm = 0u;
        const int base = t0 + tid * 32;
        for (int j = 0; j < 32; ++j) {
            int e = base + j;
            if (e < E0) {
                int uu = U[e], vv = V[e];
                if (uu != vv) {
                    unsigned rc = ((unsigned)vv << 12) | (unsigned)uu;
                    unsigned old = atomicOr(&BM[rc >> 5], 0u);   // L2 read
                    if (!((old >> (rc & 31)) & 1u)) fm |= (1u << j);
                }
            }
        }
        int tot;
        int off = blockScanExcl(__popc(fm), s_w, &tot);
        int r = s_bc[5] + off;
        unsigned m = fm;
        while (m) {
            int j = __ffs((int)m) - 1; m &= m - 1;
            int e = base + j;
            U[E0 + r] = V[e]; V[E0 + r] = U[e];
            ++r;
        }
        __syncthreads();
        if (tid == 0) s_bc[5] += tot;
        __syncthreads();
    }
    const int E1 = E0 + s_bc[5];

    // ---- build static CSR, OUT-endpoint only ----
    // After the append the arc SET is symmetric, so out-neighbors == all neighbors;
    // stamp dedup in A2 eats multiplicity differences. Halves list length + scatter.
    for (int n = tid; n < NNODES; n += NT) s_roff[n] = 0;
    __syncthreads();
    for (int e = tid; e < E1; e += NT) {
        int uu = U[e], vv = V[e];
        if (uu != vv) atomicAdd(&s_roff[uu], 1);
    }
    __syncthreads();
    {
        int n0 = tid * 4;
        int c0 = s_roff[n0], c1 = s_roff[n0 + 1], c2 = s_roff[n0 + 2], c3 = s_roff[n0 + 3];
        int tot;
        int off = blockScanExcl(c0 + c1 + c2 + c3, s_w, &tot);
        int st = off;
        s_roff[n0] = st;     s_rend[n0] = st;     st += c0;
        s_roff[n0 + 1] = st; s_rend[n0 + 1] = st; st += c1;
        s_roff[n0 + 2] = st; s_rend[n0 + 2] = st; st += c2;
        s_roff[n0 + 3] = st; s_rend[n0 + 3] = st;
    }
    __syncthreads();
    for (int e = tid; e < E1; e += NT) {
        int uu = U[e], vv = V[e];
        if (uu != vv) {
            int p = atomicAdd(&s_rend[uu], 1);
            OTH[p] = vv;
        }
    }
    __syncthreads();
    {   // flush iter-0 staged H into global NBR
        const int cnt0 = s_bc[2];
        for (int i = tid; i < cnt0; i += NT) NBR[i] = s_tmp[i];
    }
    // ---- dump handoff state ----
    for (int i = tid; i < NNODES; i += NT) {
        int nd = (int)s_order[i];
        ORDV[i]  = nd | (s_vis[nd] ? 0x8000 : 0);
        ROFFG[i] = s_roff[i];
        RENDG[i] = s_rend[i];
    }
    if (tid == 0) { HAND[0] = E1; HAND[1] = s_bc[2]; HAND[2] = s_bc[0]; }
}

// ================= Phase A2: main loop, SINGLE WAVE, zero barriers =================
__global__ __launch_bounds__(64, 1)
void phaseA2(const int* __restrict__ OTH, int* __restrict__ NBR,
             const int* __restrict__ ORDV, const int* __restrict__ ROFFG,
             const int* __restrict__ RENDG, const int* __restrict__ HAND,
             int* __restrict__ SEL, int* __restrict__ CNTS,
             int* __restrict__ NST, int* __restrict__ FIL, int* __restrict__ SC,
             int* __restrict__ LABG, int* __restrict__ RNKG)
{
    __shared__ unsigned short s_ordvis[NNODES];   // visbit(0x8000) | node id
    __shared__ unsigned short s_pos[NNODES];      // inverse permutation
    __shared__ unsigned short s_lab[NNODES];      // lazy label (chain <= 1)
    __shared__ unsigned short s_so[NNODES];       // selection order
    __shared__ int s_cnt[NNODES];                 // per-iteration |H_k|
    __shared__ int s_stamp[NNODES];               // dedup epoch; reused as rank
    __shared__ int s_roff[NNODES];
    __shared__ int s_rend[NNODES];
    __shared__ unsigned char s_sel[NNODES];

    const int ln = threadIdx.x;                   // single wave: tid == lane
    const unsigned long long ltm = (1ull << ln) - 1ull;
    const int cnt0 = HAND[1], hub0 = HAND[2];

    for (int i = ln; i < NNODES; i += 64) {
        int ov = ORDV[i];
        s_ordvis[i] = (unsigned short)ov;
        s_pos[ov & 0x7FFF] = (unsigned short)i;
        s_roff[i] = ROFFG[i];
        s_rend[i] = RENDG[i];
        s_lab[i] = (unsigned short)i;
        s_stamp[i] = 0; s_sel[i] = 0; s_cnt[i] = 0;
    }
    if (ln == 0) {
        s_sel[hub0] = 1; s_so[0] = (unsigned short)hub0;
        s_cnt[0] = cnt0;
    }
    // single wave: instruction order + lgkmcnt waits give LDS visibility; no barrier.

    // NBR cursor lives in a wave-uniform REGISTER (was an LDS atomic — serialized).
    int nc = cnt0;
    int p = 0, k = 1;
    // speculative next-hub prefetch state
    int pf_node = -1, pf_rb = 0, pf_re = 0, pf_val = -1;

    for (;;) {
        // ---- selection: one 64-wide window ballot per step (wave-uniform) ----
        int node = -1;
        while (p < NNODES) {
            int idx = p + ln;
            int ov = (idx < NNODES) ? (int)s_ordvis[idx] : 0x8000;
            unsigned long long bal = __ballot(!(ov & 0x8000));
            if (bal != 0ull) {
                int sl = __ffsll((long long)bal) - 1;
                node = __shfl(ov, sl, 64) & 0x7FFF;
                p += sl + 1;
                break;
            }
            p += 64;
        }
        if (node < 0) break;
        if (ln == 0) { s_sel[node] = 1; s_so[k] = (unsigned short)node; }

        // use prefetched row if the speculation hit (common case)
        int rb, re, v0;
        if (node == pf_node) { rb = pf_rb; re = pf_re; v0 = pf_val; }
        else {
            rb = s_roff[node]; re = s_rend[node];
            v0 = (rb + ln < re) ? OTH[rb + ln] : -1;
        }

        // ---- speculative scan for NEXT hub + issue its OTH load NOW ----
        // Marks only ever ADD visited, so everything before the candidate stays
        // visited: advancing p to the candidate's position is always safe, and the
        // only failure mode is candidate ∈ H_k, caught by the node==pf_node check.
        {
            int q = p, cand = -1, cidx = NNODES;
            while (q < NNODES) {
                int idx = q + ln;
                int ov = (idx < NNODES) ? (int)s_ordvis[idx] : 0x8000;
                unsigned long long bal = __ballot(!(ov & 0x8000));
                if (bal != 0ull) {
                    int sl = __ffsll((long long)bal) - 1;
                    cand = __shfl(ov, sl, 64) & 0x7FFF;
                    cidx = q + sl;
                    break;
                }
                q += 64;
            }
            p = (cand >= 0) ? cidx : NNODES;
            pf_node = cand;
            if (cand >= 0) {
                pf_rb = s_roff[cand]; pf_re = s_rend[cand];
                pf_val = (pf_rb + ln < pf_re) ? OTH[pf_rb + ln] : -1;   // flies during processing
            } else pf_val = -1;
        }

        // ---- process hub's (out-)neighbor list ----
        const int begin = nc;
        auto proc = [&](int o) {
            int w = (o >= 0) ? (int)s_lab[o] : node;    // sentinel skips via w==node
            bool cnd = (w != node);
            int old = k;
            if (cnd) old = atomicMax(&s_stamp[w], k);
            bool nw = cnd && (old < k);
            unsigned long long bal = __ballot(nw);
            if (nw) {
                int pre = __popcll(bal & ltm);
                NBR[nc + pre] = w;
                s_ordvis[s_pos[w]] = (unsigned short)(0x8000 | w);
                if (!s_sel[w]) s_lab[w] = (unsigned short)node;
            }
            nc += __popcll(bal);                        // wave-uniform cursor update
        };
        proc(v0);
        for (int s0 = rb + 64; s0 < re; s0 += 64) {     // rare: out-degree > 64
            int o = (s0 + ln < re) ? OTH[s0 + ln] : -1;
            proc(o);
        }
        if (ln == 0) s_cnt[k] = nc - begin;
        k++;
    }
    const int K = k;

    // ---- rank of selected nodes among sorted(select); store into s_stamp ----
    {
        int base = 0;
        for (int c = 0; c < NNODES / 64; ++c) {
            int n = c * 64 + ln;
            int f = s_sel[n];
            unsigned long long b = __ballot(f);
            s_stamp[n] = base + __popcll(b & ltm);
            base += __popcll(b);
        }
    }
    // ---- SEL / CNTS / NST (exclusive prefix of CNTS) ----
    {
        int nb = 0;
        for (int c = 0; c * 64 < K; ++c) {
            int i = c * 64 + ln;
            int cv = (i < K) ? s_cnt[i] : 0;
            int x = cv;
#pragma unroll
            for (int off = 1; off < 64; off <<= 1) {
                int t = __shfl_up(x, off, 64);
                if (ln >= off) x += t;
            }
            if (i < K) { NST[i] = nb + x - cv; CNTS[i] = cv; SEL[i] = (int)s_so[i]; }
            nb += __shfl(x, 63, 64);
        }
    }
    // ---- FIL forward-fill via ballot + clz ----
    {
        int carry = 0;
        for (int c = 0; c * 64 < K; ++c) {
            int i = c * 64 + ln;
            int f = (i < K) && (s_cnt[i] > 0);
            unsigned long long b = __ballot(f);
            unsigned long long m = b & ((ln == 63) ? ~0ull : ((1ull << (ln + 1)) - 1ull));
            int fil = m ? (c * 64 + 63 - __clzll(m)) : carry;
            if (i < K) FIL[i] = fil;
            carry = b ? (c * 64 + 63 - __clzll(b)) : carry;
        }
    }
    if (ln == 0) SC[0] = K;
    // ---- dump labels + ranks for A3 ----
    for (int i = ln; i < NNODES; i += 64) {
        LABG[i] = (int)s_lab[i];
        RNKG[i] = s_stamp[i];
    }
}

// ================= Phase A3: final arc compaction + remap (NT=1024) =================
__global__ __launch_bounds__(NT, 1)
void phaseA3(const int* __restrict__ U, const int* __restrict__ V,
             const int* __restrict__ LABG, const int* __restrict__ RNKG,
             const int* __restrict__ HAND, int* __restrict__ SC,
             int* __restrict__ TMP, float* __restrict__ out)
{
    __shared__ unsigned short l_lab[NNODES];
    __shared__ int l_rnk[NNODES];
    __shared__ int s_w[16];
    __shared__ int s_base[1];

    const int tid = threadIdx.x;
    for (int i = tid; i < NNODES; i += NT) {
        l_lab[i] = (unsigned short)LABG[i];
        l_rnk[i] = RNKG[i];
    }
    if (tid == 0) s_base[0] = 0;
    __syncthreads();

    const int E1 = HAND[0];
    const int K  = SC[0];
    const size_t obase = (size_t)K * 8192;

    // single-pass ordered compaction: 64 arcs/thread bitmask + one block scan
    for (int t0 = 0; t0 < E1; t0 += NT * 64) {
        unsigned long long fm = 0ull;
        const int base = t0 + tid * 64;
        if (base + 64 <= E1) {                   // vectorized int4 loads
            const int4* U4 = (const int4*)(U + base);
            const int4* V4 = (const int4*)(V + base);
#pragma unroll
            for (int q = 0; q < 16; ++q) {
                int4 a = U4[q], b = V4[q];
                int j = q * 4;
                if ((int)l_lab[a.x] != (int)l_lab[b.x]) fm |= 1ull << j;
                if ((int)l_lab[a.y] != (int)l_lab[b.y]) fm |= 1ull << (j + 1);
                if ((int)l_lab[a.z] != (int)l_lab[b.z]) fm |= 1ull << (j + 2);
                if ((int)l_lab[a.w] != (int)l_lab[b.w]) fm |= 1ull << (j + 3);
            }
        } else {
            for (int j = 0; j < 64; ++j) {
                int e = base + j;
                if (e < E1) {
                    if ((int)l_lab[U[e]] != (int)l_lab[V[e]]) fm |= 1ull << j;
                }
            }
        }
        int tot;
        int off = blockScanExcl(__popcll(fm), s_w, &tot);
        int r = s_base[0] + off;
        unsigned long long m = fm;
        while (m) {
            int j = __ffsll((long long)m) - 1; m &= m - 1;
            int e = base + j;
            out[obase + (size_t)r] = (float)l_rnk[(int)l_lab[U[e]]];
            TMP[r] = l_rnk[(int)l_lab[V[e]]];
            ++r;
        }
        __syncthreads();
        if (tid == 0) s_base[0] += tot;
        __syncthreads();
    }
    const int Ef = s_base[0];
    if (tid == 0) SC[1] = Ef;
    for (int r = tid; r < Ef; r += NT)
        out[obase + (size_t)Ef + (size_t)r] = (float)TMP[r];
}

// ---------------- Phase B: END rows (Dv | mean) with fill indirection ----------------
__global__ __launch_bounds__(256, 4)
void phaseB(const float* __restrict__ x,
            const float* __restrict__ W1, const float* __restrict__ W2,
            const float* __restrict__ B1, const float* __restrict__ B2,
            const int* __restrict__ NBR, const int* __restrict__ SEL,
            const int* __restrict__ CNTS, const int* __restrict__ NST,
            const int* __restrict__ FIL, const int* __restrict__ SC,
            float* __restrict__ out)
{
    const int K = SC[0];
    const int k = blockIdx.x;
    if (k >= K) return;
    const int kk   = FIL[k];
    const int node = SEL[kk];
    const int cnt  = CNTS[kk];
    const int st   = NST[kk];
    const int tid  = threadIdx.x;
    const float4* x4 = (const float4*)x;

    float4 acc[4];
#pragma unroll
    for (int j = 0; j < 4; j++) acc[j] = make_float4(0.f, 0.f, 0.f, 0.f);

    for (int r = 0; r < cnt; ++r) {
        const float4* row = x4 + (size_t)NBR[st + r] * 1024;
#pragma unroll
        for (int j = 0; j < 4; j++) {
            float4 t = row[tid + j * 256];
            acc[j].x += t.x; acc[j].y += t.y; acc[j].z += t.z; acc[j].w += t.w;
        }
    }

    const float fc  = (float)cnt;
    const float inv = 1.0f / (float)(cnt > 1 ? cnt : 1);
    const float4* xr = x4 + (size_t)node * 1024;
    float4* o4 = (float4*)(out + (size_t)k * 8192);

#pragma unroll
    for (int j = 0; j < 4; j++) {
        int c = tid + j * 256;
        float4 w1 = ((const float4*)W1)[c], b1 = ((const float4*)B1)[c];
        float4 w2 = ((const float4*)W2)[c], b2 = ((const float4*)B2)[c];
        float4 xv = xr[c];
        float4 pd, pm;
        pd.x = xv.x * w2.x + b2.x;
        pd.y = xv.y * w2.y + b2.y;
        pd.z = xv.z * w2.z + b2.z;
        pd.w = xv.w * w2.w + b2.w;
        pm.x = (acc[j].x * w1.x + fc * b1.x) * inv;
        pm.y = (acc[j].y * w1.y + fc * b1.y) * inv;
        pm.z = (acc[j].z * w1.z + fc * b1.z) * inv;
        pm.w = (acc[j].w * w1.w + fc * b1.w) * inv;
        o4[c] = pd;
        o4[1024 + c] = pm;
    }
}

extern "C" void kernel_launch(void* const* d_in, const int* in_sizes, int n_in,
                              void* d_out, int out_size, void* d_ws, size_t ws_size,
                              hipStream_t stream)
{
    const float* x  = (const float*)d_in[0];
    const int*   ei = (const int*)d_in[1];
    const float* W1 = (const float*)d_in[2];
    const float* W2 = (const float*)d_in[3];
    const float* B1 = (const float*)d_in[4];
    const float* B2 = (const float*)d_in[5];
    const int E0 = in_sizes[1] / 2;

    char* w = (char*)d_ws;
    int* U = (int*)w;                         // [ECAP]
    int* V = U + ECAP;                        // [ECAP]
    unsigned int* BM = (unsigned int*)(V + ECAP);   // 2 MB bitmap (iter-0 only)
    int* OTH = (int*)BM;                      // [2*ECAP] static CSR other-endpoint
    int* NBR = OTH + 2 * ECAP;                // [2*ECAP]
    int* TMP = NBR + 2 * ECAP;                // [2*ECAP] A3 scratch
    char* meta = (char*)BM + (2u << 20);
    int* SEL   = (int*)meta;
    int* CNTS  = SEL  + NNODES;
    int* NST   = CNTS + NNODES;
    int* FIL   = NST  + NNODES;
    int* SC    = FIL  + NNODES;               // [16]
    int* ORDV  = SC   + 16;
    int* ROFFG = ORDV + NNODES;
    int* RENDG = ROFFG + NNODES;
    int* LABG  = RENDG + NNODES;
    int* RNKG  = LABG + NNODES;
    int* HAND  = RNKG + NNODES;               // [16]
    float* out = (float*)d_out;

    // grid-parallel zero of the 2MB BM bitmap (plain kernel; graph-capture-safe)
    hipLaunchKernelGGL(zeroBM, dim3(512), dim3(256), 0, stream, (int4*)BM);

    hipLaunchKernelGGL(phaseA1, dim3(1), dim3(NT), 0, stream,
                       ei, E0, U, V, BM, NBR, OTH, ORDV, ROFFG, RENDG, HAND);
    hipLaunchKernelGGL(phaseA2, dim3(1), dim3(64), 0, stream,
                       OTH, NBR, ORDV, ROFFG, RENDG, HAND,
                       SEL, CNTS, NST, FIL, SC, LABG, RNKG);
    hipLaunchKernelGGL(phaseA3, dim3(1), dim3(NT), 0, stream,
                       U, V, LABG, RNKG, HAND, SC, TMP, out);
    hipLaunchKernelGGL(phaseB, dim3(NNODES), dim3(256), 0, stream,
                       x, W1, W2, B1, B2, NBR, SEL, CNTS, NST, FIL, SC, out);
}

// Round 3
// 1060.772 us; speedup vs baseline: 1.1220x; 1.1220x over previous
//
#include <hip/hip_runtime.h>
#include <hip/hip_bf16.h>

#define NT 1024
#define NNODES 4096
#define ECAP 65536   // max arcs after iteration-1 symmetrization (E0 <= 32768)

// ---------------- grid-parallel 2MB bitmap zero (replaces hipMemsetAsync) ----------------
__global__ __launch_bounds__(256)
void zeroBM(int4* __restrict__ bm) {
    bm[(size_t)blockIdx.x * 256 + threadIdx.x] = make_int4(0, 0, 0, 0);
}

// ---------------- block-wide exclusive scan over NT=1024 values ----------------
__device__ __forceinline__ int blockScanExcl(int v, int* s_w, int* total) {
    const int tid  = threadIdx.x;
    const int lane = tid & 63;
    const int wv   = tid >> 6;
    int x = v;
#pragma unroll
    for (int off = 1; off < 64; off <<= 1) {
        int t = __shfl_up(x, off, 64);
        if (lane >= off) x += t;
    }
    if (lane == 63) s_w[wv] = x;
    __syncthreads();
    if (tid < 16) {
        int y = s_w[tid];
#pragma unroll
        for (int off = 1; off < 16; off <<= 1) {
            int t = __shfl_up(y, off, 16);
            if (tid >= off) y += t;
        }
        s_w[tid] = y;
    }
    __syncthreads();
    int base = wv ? s_w[wv - 1] : 0;
    int tot  = s_w[15];
    __syncthreads();   // protect s_w reuse
    *total = tot;
    return base + x - v;   // exclusive prefix
}

// ================= Phase A1: preamble (R4-exact), dump handoff state =================
// s_bc slots: 0=node 2=nbrCnt 4=orderBase 5=appendBase 7=maxdeg 9=not64
__global__ __launch_bounds__(NT, 1)
void phaseA1(const int* __restrict__ ei, int E0,
             int* __restrict__ U, int* __restrict__ V,
             unsigned int* __restrict__ BM,
             int* __restrict__ NBR, int* __restrict__ OTH,
             int* __restrict__ ORDV, int* __restrict__ ROFFG, int* __restrict__ RENDG,
             int* __restrict__ HAND)
{
    __shared__ unsigned short s_order[NNODES];
    __shared__ unsigned char  s_vis[NNODES];
    __shared__ unsigned char  s_rank[NNODES];     // counting-sort within-group rank
    __shared__ unsigned int   s_hb[NNODES / 32];
    __shared__ int s_roff[NNODES];
    __shared__ int s_rend[NNODES];
    __shared__ int s_tmp[NNODES];
    __shared__ int s_mat[64][65];                 // [deg][group] counts / prefixes; col 64 = desc base
    __shared__ int s_w[16];
    __shared__ int s_bc[16];

    const int tid = threadIdx.x;

    for (int i = tid; i < NNODES; i += NT) { s_vis[i] = 0; s_tmp[i] = 0; }
    for (int i = tid; i < NNODES / 32; i += NT) s_hb[i] = 0;
    if (tid < 16) s_bc[tid] = 0;
    __syncthreads();

    // ---- detect int64 vs int32 edge buffer ----
    for (int i = tid; i < E0; i += NT)
        if (ei[2 * i + 1] != 0) s_bc[9] = 1;
    __syncthreads();
    const int is64 = !s_bc[9];

    // ---- copy edges + degree histogram (I+O) ----
    for (int e = tid; e < E0; e += NT) {
        int uu = ei[is64 ? 2 * e : e];
        int vv = ei[is64 ? 2 * (E0 + e) : (E0 + e)];
        U[e] = uu; V[e] = vv;
        atomicAdd(&s_tmp[uu], 1);
        atomicAdd(&s_tmp[vv], 1);
    }
    __syncthreads();
    for (int n = tid; n < NNODES; n += NT) atomicMax(&s_bc[7], s_tmp[n]);
    __syncthreads();
    const int maxd = s_bc[7];

    // ---- stable argsort by descending degree ----
    if (maxd < 64) {
        // fast path: stable counting sort, ~5 barriers total.
        const int wv = tid >> 6, lane = tid & 63;
        const unsigned long long ltm = (1ull << lane) - 1ull;
        for (int g = wv; g < 64; g += 16) {
            int n = g * 64 + lane;
            int d = s_tmp[n];
            int rk = 0;
            for (int dd = 0; dd < 64; ++dd) {
                unsigned long long bal = __ballot(d == dd);
                if (lane == 0) s_mat[dd][g] = __popcll(bal);
                if (d == dd) rk = __popcll(bal & ltm);
            }
            s_rank[n] = (unsigned char)rk;
        }
        __syncthreads();
        if (tid < 64) {                      // per-degree prefix across the 64 id-groups
            int run = 0;
            for (int g = 0; g < 64; ++g) { int t = s_mat[tid][g]; s_mat[tid][g] = run; run += t; }
            s_mat[tid][64] = run;            // total per degree
        }
        __syncthreads();
        if (tid < 64) {                      // descending-degree exclusive base
            int x = s_mat[tid][64];
#pragma unroll
            for (int off = 1; off < 64; off <<= 1) {
                int t = __shfl_up(x, off, 64);
                if (tid >= off) x += t;
            }
            int T = __shfl(x, 63, 64);
            s_mat[tid][64] = T - x;          // sum of bins with degree > tid
        }
        __syncthreads();
        for (int g = wv; g < 64; g += 16) {
            int n = g * 64 + lane;
            int d = s_tmp[n];
            int pos = s_mat[d][64] + s_mat[d][g] + (int)s_rank[n];
            s_order[pos] = (unsigned short)n;
        }
        __syncthreads();
    } else {
        // legacy fallback (exact, slow): one scan round per degree value
        for (int d = maxd; d >= 0; --d) {
            int n0 = tid * 4;
            int f0 = (s_tmp[n0] == d), f1 = (s_tmp[n0 + 1] == d);
            int f2 = (s_tmp[n0 + 2] == d), f3 = (s_tmp[n0 + 3] == d);
            int tot;
            int off = blockScanExcl(f0 + f1 + f2 + f3, s_w, &tot);
            int idx = s_bc[4] + off;
            if (f0) s_order[idx++] = (unsigned short)n0;
            if (f1) s_order[idx++] = (unsigned short)(n0 + 1);
            if (f2) s_order[idx++] = (unsigned short)(n0 + 2);
            if (f3) s_order[idx++] = (unsigned short)(n0 + 3);
            __syncthreads();
            if (tid == 0) s_bc[4] += tot;
            __syncthreads();
        }
    }

    // ---- iteration 0 (full-array scans, eager relabel) ----
    if (tid == 0) {
        int nd = s_order[0];
        s_bc[0] = nd; s_vis[nd] = 1;
    }
    __syncthreads();
    {
        const int node = s_bc[0];
        for (int e = tid; e < E0; e += NT) {
            int uu = U[e], vv = V[e];
            if (uu == node) {
                int w = vv; unsigned m = 1u << (w & 31);
                unsigned old = atomicOr(&s_hb[w >> 5], m);
                if (!(old & m)) { int i = atomicAdd(&s_bc[2], 1); s_tmp[i] = w; s_vis[w] = 1; }
            }
            if (vv == node) {
                int w = uu; unsigned m = 1u << (w & 31);
                unsigned old = atomicOr(&s_hb[w >> 5], m);
                if (!(old & m)) { int i = atomicAdd(&s_bc[2], 1); s_tmp[i] = w; s_vis[w] = 1; }
            }
        }
        __syncthreads();
        // eager relabel Hn = H \ {node} (U/V frozen afterwards)
        for (int e = tid; e < E0; e += NT) {
            int uu = U[e];
            if (uu != node && ((s_hb[uu >> 5] >> (uu & 31)) & 1)) U[e] = node;
            int vv = V[e];
            if (vv != node && ((s_hb[vv >> 5] >> (vv & 31)) & 1)) V[e] = node;
        }
        __syncthreads();
    }

    // ---- symmetry append (only iteration ever needing it) ----
    // BM is pre-zeroed by the grid-parallel zeroBM kernel on the stream.
    for (int e = tid; e < E0; e += NT) {
        int uu = U[e], vv = V[e];
        if (uu != vv) {
            unsigned code = ((unsigned)uu << 12) | (unsigned)vv;
            atomicOr(&BM[code >> 5], 1u << (code & 31));
        }
    }
    __syncthreads();
    // single-pass ordered compaction: 32 arcs/thread bitmask + one block scan per 32K chunk
    for (int t0 = 0; t0 < E0; t0 += NT * 32) {
        unsigned fm = 0u;
        const int base = t0 + tid * 32;
        for (int j = 0; j < 32; ++j) {
            int e = base + j;
            if (e < E0) {
                int uu = U[e], vv = V[e];
                if (uu != vv) {
                    unsigned rc = ((unsigned)vv << 12) | (unsigned)uu;
                    unsigned old = atomicOr(&BM[rc >> 5], 0u);   // L2 read
                    if (!((old >> (rc & 31)) & 1u)) fm |= (1u << j);
                }
            }
        }
        int tot;
        int off = blockScanExcl(__popc(fm), s_w, &tot);
        int r = s_bc[5] + off;
        unsigned m = fm;
        while (m) {
            int j = __ffs((int)m) - 1; m &= m - 1;
            int e = base + j;
            U[E0 + r] = V[e]; V[E0 + r] = U[e];
            ++r;
        }
        __syncthreads();
        if (tid == 0) s_bc[5] += tot;
        __syncthreads();
    }
    const int E1 = E0 + s_bc[5];

    // ---- build static CSR, OUT-endpoint only ----
    for (int n = tid; n < NNODES; n += NT) s_roff[n] = 0;
    __syncthreads();
    for (int e = tid; e < E1; e += NT) {
        int uu = U[e], vv = V[e];
        if (uu != vv) atomicAdd(&s_roff[uu], 1);
    }
    __syncthreads();
    {
        int n0 = tid * 4;
        int c0 = s_roff[n0], c1 = s_roff[n0 + 1], c2 = s_roff[n0 + 2], c3 = s_roff[n0 + 3];
        int tot;
        int off = blockScanExcl(c0 + c1 + c2 + c3, s_w, &tot);
        int st = off;
        s_roff[n0] = st;     s_rend[n0] = st;     st += c0;
        s_roff[n0 + 1] = st; s_rend[n0 + 1] = st; st += c1;
        s_roff[n0 + 2] = st; s_rend[n0 + 2] = st; st += c2;
        s_roff[n0 + 3] = st; s_rend[n0 + 3] = st;
    }
    __syncthreads();
    for (int e = tid; e < E1; e += NT) {
        int uu = U[e], vv = V[e];
        if (uu != vv) {
            int p = atomicAdd(&s_rend[uu], 1);
            OTH[p] = vv;
        }
    }
    __syncthreads();
    {   // flush iter-0 staged H into global NBR
        const int cnt0 = s_bc[2];
        for (int i = tid; i < cnt0; i += NT) NBR[i] = s_tmp[i];
    }
    // ---- dump handoff state ----
    for (int i = tid; i < NNODES; i += NT) {
        int nd = (int)s_order[i];
        ORDV[i]  = nd | (s_vis[nd] ? 0x8000 : 0);
        ROFFG[i] = s_roff[i];
        RENDG[i] = s_rend[i];
    }
    if (tid == 0) { HAND[0] = E1; HAND[1] = s_bc[2]; HAND[2] = s_bc[0]; }
}

// ================= Phase A2: main loop, SINGLE WAVE, zero barriers =================
// Pair-processing: select first TWO unvisited hubs from one bitmask snapshot,
// issue both OTH row loads together (one shared L2 wait), process sequentially
// with a free invalidation watch (c2 absorbed by H(c1) ~2-5% of pairs).
__global__ __launch_bounds__(64, 1)
void phaseA2(const int* __restrict__ OTH, int* __restrict__ NBR,
             const int* __restrict__ ORDV, const int* __restrict__ ROFFG,
             const int* __restrict__ RENDG, const int* __restrict__ HAND,
             int* __restrict__ SEL, int* __restrict__ CNTS,
             int* __restrict__ NST, int* __restrict__ FIL, int* __restrict__ SC,
             int* __restrict__ LABG, int* __restrict__ RNKG)
{
    __shared__ unsigned short s_ord[NNODES];      // selection order (node ids)
    __shared__ unsigned int   s_visbits[NNODES / 32];  // visited bit per ORDER SLOT
    __shared__ unsigned short s_pos[NNODES];      // node -> order slot
    __shared__ unsigned short s_lab[NNODES];      // lazy label (chain <= 1, targets hubs)
    __shared__ unsigned short s_so[NNODES];       // selection order of hubs
    __shared__ int s_cnt[NNODES];                 // per-iteration |H_k|
    __shared__ int s_stamp[NNODES];               // dedup epoch; reused as rank
    __shared__ int s_roff[NNODES];
    __shared__ int s_rend[NNODES];
    __shared__ unsigned char s_sel[NNODES];

    const int ln = threadIdx.x;                   // single wave: tid == lane
    const unsigned long long ltm = (1ull << ln) - 1ull;
    const int cnt0 = HAND[1], hub0 = HAND[2];

    for (int i = ln; i < NNODES / 32; i += 64) s_visbits[i] = 0u;
    for (int i = ln; i < NNODES; i += 64) {
        int ov = ORDV[i];
        int nd = ov & 0x7FFF;
        s_ord[i] = (unsigned short)nd;
        s_pos[nd] = (unsigned short)i;
        s_roff[i] = ROFFG[i];
        s_rend[i] = RENDG[i];
        s_lab[i] = (unsigned short)i;
        s_stamp[i] = 0; s_sel[i] = 0; s_cnt[i] = 0;
        if (ov & 0x8000) atomicOr(&s_visbits[i >> 5], 1u << (i & 31));
    }
    if (ln == 0) {
        s_sel[hub0] = 1; s_so[0] = (unsigned short)hub0;
        s_cnt[0] = cnt0;
    }
    // single wave: instruction order + lgkmcnt waits give LDS visibility; no barrier.

    int nc = cnt0;   // NBR cursor, wave-uniform register
    int k = 1;

    // first TWO unvisited order-slots from the full 4096-slot bitmask.
    // lane ln covers words {ln, ln+64} (slots [32ln,32ln+32) and +2048).
    auto select2 = [&](int& c1, int& c2) {
        unsigned lo = ~s_visbits[ln];
        unsigned hi = ~s_visbits[ln + 64];
        unsigned long long ball = __ballot(lo != 0u);
        unsigned long long balh = __ballot(hi != 0u);
        c1 = -1; c2 = -1;
        int slot2 = -1;
        if (ball) {
            int sl = __ffsll((long long)ball) - 1;
            unsigned ww = __shfl(lo, sl, 64);
            int slot1 = sl * 32 + __ffs((int)ww) - 1;
            c1 = (int)s_ord[slot1];
            unsigned wwb = ww & (ww - 1);
            if (wwb) slot2 = sl * 32 + __ffs((int)wwb) - 1;
            else {
                unsigned long long ball2 = ball & (ball - 1);
                if (ball2) {
                    int sl2 = __ffsll((long long)ball2) - 1;
                    unsigned ww2 = __shfl(lo, sl2, 64);
                    slot2 = sl2 * 32 + __ffs((int)ww2) - 1;
                } else if (balh) {
                    int sl2 = __ffsll((long long)balh) - 1;
                    unsigned ww2 = __shfl(hi, sl2, 64);
                    slot2 = 2048 + sl2 * 32 + __ffs((int)ww2) - 1;
                }
            }
        } else if (balh) {
            int sl = __ffsll((long long)balh) - 1;
            unsigned ww = __shfl(hi, sl, 64);
            int slot1 = 2048 + sl * 32 + __ffs((int)ww) - 1;
            c1 = (int)s_ord[slot1];
            unsigned wwb = ww & (ww - 1);
            if (wwb) slot2 = 2048 + sl * 32 + __ffs((int)wwb) - 1;
            else {
                unsigned long long balh2 = balh & (balh - 1);
                if (balh2) {
                    int sl2 = __ffsll((long long)balh2) - 1;
                    unsigned ww2 = __shfl(hi, sl2, 64);
                    slot2 = 2048 + sl2 * 32 + __ffs((int)ww2) - 1;
                }
            }
        }
        if (slot2 >= 0) c2 = (int)s_ord[slot2];
    };

    auto select1 = [&](int& c) {
        unsigned lo = ~s_visbits[ln];
        unsigned hi = ~s_visbits[ln + 64];
        unsigned long long ball = __ballot(lo != 0u);
        unsigned long long balh = __ballot(hi != 0u);
        c = -1;
        if (ball) {
            int sl = __ffsll((long long)ball) - 1;
            unsigned ww = __shfl(lo, sl, 64);
            c = (int)s_ord[sl * 32 + __ffs((int)ww) - 1];
        } else if (balh) {
            int sl = __ffsll((long long)balh) - 1;
            unsigned ww = __shfl(hi, sl, 64);
            c = (int)s_ord[2048 + sl * 32 + __ffs((int)ww) - 1];
        }
    };

    // process hub's row; stamp = current k; returns true iff `watch` freshly absorbed
    auto procRow = [&](int hub, int rb, int re, int o0, int watch) -> bool {
        bool invw = false;
        int o = o0;
        for (int s0 = rb; s0 < re; s0 += 64) {
            int w = (o >= 0) ? (int)s_lab[o] : hub;     // sentinel skips via w==hub
            bool cnd = (w != hub);
            int old = k;
            if (cnd) old = atomicMax(&s_stamp[w], k);
            bool nw = cnd && (old < k);
            unsigned long long bal = __ballot(nw);
            if (nw) {
                int pre = __popcll(bal & ltm);
                NBR[nc + pre] = w;
                int slot = (int)s_pos[w];
                atomicOr(&s_visbits[slot >> 5], 1u << (slot & 31));
                if (!s_sel[w]) s_lab[w] = (unsigned short)hub;
            }
            nc += __popcll(bal);                        // wave-uniform cursor update
            invw = invw || (__ballot(nw && (w == watch)) != 0ull);
            int s1 = s0 + 64;                           // rare: out-degree > 64
            o = (s1 + ln < re) ? OTH[s1 + ln] : -1;
        }
        return invw;
    };

    for (;;) {
        int c1, c2;
        select2(c1, c2);
        if (c1 < 0) break;

        // both CSR rows + both OTH loads issue together -> one shared L2 wait
        int rb1 = s_roff[c1], re1 = s_rend[c1];
        int rb2 = (c2 >= 0) ? s_roff[c2] : 0;
        int re2 = (c2 >= 0) ? s_rend[c2] : 0;
        int oA = (rb1 + ln < re1) ? OTH[rb1 + ln] : -1;
        int oB = (c2 >= 0 && rb2 + ln < re2) ? OTH[rb2 + ln] : -1;

        if (ln == 0) {
            s_sel[c1] = 1; s_so[k] = (unsigned short)c1;
            int sl1 = (int)s_pos[c1];
            atomicOr(&s_visbits[sl1 >> 5], 1u << (sl1 & 31));
            if (c2 >= 0) {   // pre-mark c2 visited (idempotent w.r.t. absorption)
                int sl2 = (int)s_pos[c2];
                atomicOr(&s_visbits[sl2 >> 5], 1u << (sl2 & 31));
            }
        }

        int begin = nc;
        bool inval = procRow(c1, rb1, re1, oA, c2);
        if (ln == 0) s_cnt[k] = nc - begin;
        k++;

        if (c2 < 0) continue;   // <=1 unvisited existed; next select2 breaks

        if (inval) {
            // c2 absorbed into H(c1): it is merged (s_lab[c2]=c1 already applied
            // by procRow), never selected. Rescan with updated marks.
            select1(c2);
            if (c2 < 0) continue;
            rb2 = s_roff[c2]; re2 = s_rend[c2];
            oB = (rb2 + ln < re2) ? OTH[rb2 + ln] : -1;
        }
        if (ln == 0) {
            s_sel[c2] = 1; s_so[k] = (unsigned short)c2;
            int sl2 = (int)s_pos[c2];
            atomicOr(&s_visbits[sl2 >> 5], 1u << (sl2 & 31));
        }
        begin = nc;
        procRow(c2, rb2, re2, oB, -1);
        if (ln == 0) s_cnt[k] = nc - begin;
        k++;
    }
    const int K = k;

    // ---- rank of selected nodes among sorted(select); store into s_stamp ----
    {
        int base = 0;
        for (int c = 0; c < NNODES / 64; ++c) {
            int n = c * 64 + ln;
            int f = s_sel[n];
            unsigned long long b = __ballot(f);
            s_stamp[n] = base + __popcll(b & ltm);
            base += __popcll(b);
        }
    }
    // ---- SEL / CNTS / NST (exclusive prefix of CNTS) ----
    {
        int nb = 0;
        for (int c = 0; c * 64 < K; ++c) {
            int i = c * 64 + ln;
            int cv = (i < K) ? s_cnt[i] : 0;
            int x = cv;
#pragma unroll
            for (int off = 1; off < 64; off <<= 1) {
                int t = __shfl_up(x, off, 64);
                if (ln >= off) x += t;
            }
            if (i < K) { NST[i] = nb + x - cv; CNTS[i] = cv; SEL[i] = (int)s_so[i]; }
            nb += __shfl(x, 63, 64);
        }
    }
    // ---- FIL forward-fill via ballot + clz ----
    {
        int carry = 0;
        for (int c = 0; c * 64 < K; ++c) {
            int i = c * 64 + ln;
            int f = (i < K) && (s_cnt[i] > 0);
            unsigned long long b = __ballot(f);
            unsigned long long m = b & ((ln == 63) ? ~0ull : ((1ull << (ln + 1)) - 1ull));
            int fil = m ? (c * 64 + 63 - __clzll(m)) : carry;
            if (i < K) FIL[i] = fil;
            carry = b ? (c * 64 + 63 - __clzll(b)) : carry;
        }
    }
    if (ln == 0) SC[0] = K;
    // ---- dump labels + ranks for A3 ----
    for (int i = ln; i < NNODES; i += 64) {
        LABG[i] = (int)s_lab[i];
        RNKG[i] = s_stamp[i];
    }
}

// ================= Phase A3: final arc compaction + remap (NT=1024) =================
__global__ __launch_bounds__(NT, 1)
void phaseA3(const int* __restrict__ U, const int* __restrict__ V,
             const int* __restrict__ LABG, const int* __restrict__ RNKG,
             const int* __restrict__ HAND, int* __restrict__ SC,
             int* __restrict__ TMP, float* __restrict__ out)
{
    __shared__ unsigned short l_lab[NNODES];
    __shared__ int l_rnk[NNODES];
    __shared__ int s_w[16];
    __shared__ int s_base[1];

    const int tid = threadIdx.x;
    for (int i = tid; i < NNODES; i += NT) {
        l_lab[i] = (unsigned short)LABG[i];
        l_rnk[i] = RNKG[i];
    }
    if (tid == 0) s_base[0] = 0;
    __syncthreads();

    const int E1 = HAND[0];
    const int K  = SC[0];
    const size_t obase = (size_t)K * 8192;

    // single-pass ordered compaction: 64 arcs/thread bitmask + one block scan
    for (int t0 = 0; t0 < E1; t0 += NT * 64) {
        unsigned long long fm = 0ull;
        const int base = t0 + tid * 64;
        if (base + 64 <= E1) {                   // vectorized int4 loads
            const int4* U4 = (const int4*)(U + base);
            const int4* V4 = (const int4*)(V + base);
#pragma unroll
            for (int q = 0; q < 16; ++q) {
                int4 a = U4[q], b = V4[q];
                int j = q * 4;
                if ((int)l_lab[a.x] != (int)l_lab[b.x]) fm |= 1ull << j;
                if ((int)l_lab[a.y] != (int)l_lab[b.y]) fm |= 1ull << (j + 1);
                if ((int)l_lab[a.z] != (int)l_lab[b.z]) fm |= 1ull << (j + 2);
                if ((int)l_lab[a.w] != (int)l_lab[b.w]) fm |= 1ull << (j + 3);
            }
        } else {
            for (int j = 0; j < 64; ++j) {
                int e = base + j;
                if (e < E1) {
                    if ((int)l_lab[U[e]] != (int)l_lab[V[e]]) fm |= 1ull << j;
                }
            }
        }
        int tot;
        int off = blockScanExcl(__popcll(fm), s_w, &tot);
        int r = s_base[0] + off;
        unsigned long long m = fm;
        while (m) {
            int j = __ffsll((long long)m) - 1; m &= m - 1;
            int e = base + j;
            out[obase + (size_t)r] = (float)l_rnk[(int)l_lab[U[e]]];
            TMP[r] = l_rnk[(int)l_lab[V[e]]];
            ++r;
        }
        __syncthreads();
        if (tid == 0) s_base[0] += tot;
        __syncthreads();
    }
    const int Ef = s_base[0];
    if (tid == 0) SC[1] = Ef;
    for (int r = tid; r < Ef; r += NT)
        out[obase + (size_t)Ef + (size_t)r] = (float)TMP[r];
}

// ---------------- Phase B: END rows (Dv | mean) with fill indirection ----------------
__global__ __launch_bounds__(256, 4)
void phaseB(const float* __restrict__ x,
            const float* __restrict__ W1, const float* __restrict__ W2,
            const float* __restrict__ B1, const float* __restrict__ B2,
            const int* __restrict__ NBR, const int* __restrict__ SEL,
            const int* __restrict__ CNTS, const int* __restrict__ NST,
            const int* __restrict__ FIL, const int* __restrict__ SC,
            float* __restrict__ out)
{
    const int K = SC[0];
    const int k = blockIdx.x;
    if (k >= K) return;
    const int kk   = FIL[k];
    const int node = SEL[kk];
    const int cnt  = CNTS[kk];
    const int st   = NST[kk];
    const int tid  = threadIdx.x;
    const float4* x4 = (const float4*)x;

    float4 acc[4];
#pragma unroll
    for (int j = 0; j < 4; j++) acc[j] = make_float4(0.f, 0.f, 0.f, 0.f);

    for (int r = 0; r < cnt; ++r) {
        const float4* row = x4 + (size_t)NBR[st + r] * 1024;
#pragma unroll
        for (int j = 0; j < 4; j++) {
            float4 t = row[tid + j * 256];
            acc[j].x += t.x; acc[j].y += t.y; acc[j].z += t.z; acc[j].w += t.w;
        }
    }

    const float fc  = (float)cnt;
    const float inv = 1.0f / (float)(cnt > 1 ? cnt : 1);
    const float4* xr = x4 + (size_t)node * 1024;
    float4* o4 = (float4*)(out + (size_t)k * 8192);

#pragma unroll
    for (int j = 0; j < 4; j++) {
        int c = tid + j * 256;
        float4 w1 = ((const float4*)W1)[c], b1 = ((const float4*)B1)[c];
        float4 w2 = ((const float4*)W2)[c], b2 = ((const float4*)B2)[c];
        float4 xv = xr[c];
        float4 pd, pm;
        pd.x = xv.x * w2.x + b2.x;
        pd.y = xv.y * w2.y + b2.y;
        pd.z = xv.z * w2.z + b2.z;
        pd.w = xv.w * w2.w + b2.w;
        pm.x = (acc[j].x * w1.x + fc * b1.x) * inv;
        pm.y = (acc[j].y * w1.y + fc * b1.y) * inv;
        pm.z = (acc[j].z * w1.z + fc * b1.z) * inv;
        pm.w = (acc[j].w * w1.w + fc * b1.w) * inv;
        o4[c] = pd;
        o4[1024 + c] = pm;
    }
}

extern "C" void kernel_launch(void* const* d_in, const int* in_sizes, int n_in,
                              void* d_out, int out_size, void* d_ws, size_t ws_size,
                              hipStream_t stream)
{
    const float* x  = (const float*)d_in[0];
    const int*   ei = (const int*)d_in[1];
    const float* W1 = (const float*)d_in[2];
    const float* W2 = (const float*)d_in[3];
    const float* B1 = (const float*)d_in[4];
    const float* B2 = (const float*)d_in[5];
    const int E0 = in_sizes[1] / 2;

    char* w = (char*)d_ws;
    int* U = (int*)w;                         // [ECAP]
    int* V = U + ECAP;                        // [ECAP]
    unsigned int* BM = (unsigned int*)(V + ECAP);   // 2 MB bitmap (iter-0 only)
    int* OTH = (int*)BM;                      // [2*ECAP] static CSR other-endpoint
    int* NBR = OTH + 2 * ECAP;                // [2*ECAP]
    int* TMP = NBR + 2 * ECAP;                // [2*ECAP] A3 scratch
    char* meta = (char*)BM + (2u << 20);
    int* SEL   = (int*)meta;
    int* CNTS  = SEL  + NNODES;
    int* NST   = CNTS + NNODES;
    int* FIL   = NST  + NNODES;
    int* SC    = FIL  + NNODES;               // [16]
    int* ORDV  = SC   + 16;
    int* ROFFG = ORDV + NNODES;
    int* RENDG = ROFFG + NNODES;
    int* LABG  = RENDG + NNODES;
    int* RNKG  = LABG + NNODES;
    int* HAND  = RNKG + NNODES;               // [16]
    float* out = (float*)d_out;

    // grid-parallel zero of the 2MB BM bitmap (plain kernel; graph-capture-safe)
    hipLaunchKernelGGL(zeroBM, dim3(512), dim3(256), 0, stream, (int4*)BM);

    hipLaunchKernelGGL(phaseA1, dim3(1), dim3(NT), 0, stream,
                       ei, E0, U, V, BM, NBR, OTH, ORDV, ROFFG, RENDG, HAND);
    hipLaunchKernelGGL(phaseA2, dim3(1), dim3(64), 0, stream,
                       OTH, NBR, ORDV, ROFFG, RENDG, HAND,
                       SEL, CNTS, NST, FIL, SC, LABG, RNKG);
    hipLaunchKernelGGL(phaseA3, dim3(1), dim3(NT), 0, stream,
                       U, V, LABG, RNKG, HAND, SC, TMP, out);
    hipLaunchKernelGGL(phaseB, dim3(NNODES), dim3(256), 0, stream,
                       x, W1, W2, B1, B2, NBR, SEL, CNTS, NST, FIL, SC, out);
}

// Round 4
// 1047.092 us; speedup vs baseline: 1.1367x; 1.0131x over previous
//
#include <hip/hip_runtime.h>
#include <hip/hip_bf16.h>

#define NT 1024
#define NNODES 4096
#define ECAP 65536   // max arcs after iteration-1 symmetrization (E0 <= 32768)

// ---------------- grid-parallel 2MB bitmap zero (replaces hipMemsetAsync) ----------------
__global__ __launch_bounds__(256)
void zeroBM(int4* __restrict__ bm) {
    bm[(size_t)blockIdx.x * 256 + threadIdx.x] = make_int4(0, 0, 0, 0);
}

// ---------------- block-wide exclusive scan over NT=1024 values ----------------
__device__ __forceinline__ int blockScanExcl(int v, int* s_w, int* total) {
    const int tid  = threadIdx.x;
    const int lane = tid & 63;
    const int wv   = tid >> 6;
    int x = v;
#pragma unroll
    for (int off = 1; off < 64; off <<= 1) {
        int t = __shfl_up(x, off, 64);
        if (lane >= off) x += t;
    }
    if (lane == 63) s_w[wv] = x;
    __syncthreads();
    if (tid < 16) {
        int y = s_w[tid];
#pragma unroll
        for (int off = 1; off < 16; off <<= 1) {
            int t = __shfl_up(y, off, 16);
            if (tid >= off) y += t;
        }
        s_w[tid] = y;
    }
    __syncthreads();
    int base = wv ? s_w[wv - 1] : 0;
    int tot  = s_w[15];
    __syncthreads();   // protect s_w reuse
    *total = tot;
    return base + x - v;   // exclusive prefix
}

// ================= Phase A1: preamble (R4-exact), dump handoff state =================
// s_bc slots: 0=node 2=nbrCnt 4=orderBase 5=appendBase 7=maxdeg 9=not64
__global__ __launch_bounds__(NT, 1)
void phaseA1(const int* __restrict__ ei, int E0,
             int* __restrict__ U, int* __restrict__ V,
             unsigned int* __restrict__ BM,
             int* __restrict__ NBR, int* __restrict__ OTH,
             int* __restrict__ ORDV, int* __restrict__ ROFFG, int* __restrict__ RENDG,
             int* __restrict__ HAND)
{
    __shared__ unsigned short s_order[NNODES];
    __shared__ unsigned char  s_vis[NNODES];
    __shared__ unsigned char  s_rank[NNODES];     // counting-sort within-group rank
    __shared__ unsigned int   s_hb[NNODES / 32];
    __shared__ int s_roff[NNODES];
    __shared__ int s_rend[NNODES];
    __shared__ int s_tmp[NNODES];
    __shared__ int s_mat[64][65];                 // [deg][group] counts / prefixes; col 64 = desc base
    __shared__ int s_w[16];
    __shared__ int s_bc[16];

    const int tid = threadIdx.x;

    for (int i = tid; i < NNODES; i += NT) { s_vis[i] = 0; s_tmp[i] = 0; }
    for (int i = tid; i < NNODES / 32; i += NT) s_hb[i] = 0;
    if (tid < 16) s_bc[tid] = 0;
    __syncthreads();

    // ---- detect int64 vs int32 edge buffer ----
    for (int i = tid; i < E0; i += NT)
        if (ei[2 * i + 1] != 0) s_bc[9] = 1;
    __syncthreads();
    const int is64 = !s_bc[9];

    // ---- copy edges + degree histogram (I+O) ----
    for (int e = tid; e < E0; e += NT) {
        int uu = ei[is64 ? 2 * e : e];
        int vv = ei[is64 ? 2 * (E0 + e) : (E0 + e)];
        U[e] = uu; V[e] = vv;
        atomicAdd(&s_tmp[uu], 1);
        atomicAdd(&s_tmp[vv], 1);
    }
    __syncthreads();
    for (int n = tid; n < NNODES; n += NT) atomicMax(&s_bc[7], s_tmp[n]);
    __syncthreads();
    const int maxd = s_bc[7];

    // ---- stable argsort by descending degree ----
    if (maxd < 64) {
        // fast path: stable counting sort, ~5 barriers total.
        const int wv = tid >> 6, lane = tid & 63;
        const unsigned long long ltm = (1ull << lane) - 1ull;
        for (int g = wv; g < 64; g += 16) {
            int n = g * 64 + lane;
            int d = s_tmp[n];
            int rk = 0;
            for (int dd = 0; dd < 64; ++dd) {
                unsigned long long bal = __ballot(d == dd);
                if (lane == 0) s_mat[dd][g] = __popcll(bal);
                if (d == dd) rk = __popcll(bal & ltm);
            }
            s_rank[n] = (unsigned char)rk;
        }
        __syncthreads();
        if (tid < 64) {                      // per-degree prefix across the 64 id-groups
            int run = 0;
            for (int g = 0; g < 64; ++g) { int t = s_mat[tid][g]; s_mat[tid][g] = run; run += t; }
            s_mat[tid][64] = run;            // total per degree
        }
        __syncthreads();
        if (tid < 64) {                      // descending-degree exclusive base
            int x = s_mat[tid][64];
#pragma unroll
            for (int off = 1; off < 64; off <<= 1) {
                int t = __shfl_up(x, off, 64);
                if (tid >= off) x += t;
            }
            int T = __shfl(x, 63, 64);
            s_mat[tid][64] = T - x;          // sum of bins with degree > tid
        }
        __syncthreads();
        for (int g = wv; g < 64; g += 16) {
            int n = g * 64 + lane;
            int d = s_tmp[n];
            int pos = s_mat[d][64] + s_mat[d][g] + (int)s_rank[n];
            s_order[pos] = (unsigned short)n;
        }
        __syncthreads();
    } else {
        // legacy fallback (exact, slow): one scan round per degree value
        for (int d = maxd; d >= 0; --d) {
            int n0 = tid * 4;
            int f0 = (s_tmp[n0] == d), f1 = (s_tmp[n0 + 1] == d);
            int f2 = (s_tmp[n0 + 2] == d), f3 = (s_tmp[n0 + 3] == d);
            int tot;
            int off = blockScanExcl(f0 + f1 + f2 + f3, s_w, &tot);
            int idx = s_bc[4] + off;
            if (f0) s_order[idx++] = (unsigned short)n0;
            if (f1) s_order[idx++] = (unsigned short)(n0 + 1);
            if (f2) s_order[idx++] = (unsigned short)(n0 + 2);
            if (f3) s_order[idx++] = (unsigned short)(n0 + 3);
            __syncthreads();
            if (tid == 0) s_bc[4] += tot;
            __syncthreads();
        }
    }

    // ---- iteration 0 (full-array scans, eager relabel) ----
    if (tid == 0) {
        int nd = s_order[0];
        s_bc[0] = nd; s_vis[nd] = 1;
    }
    __syncthreads();
    {
        const int node = s_bc[0];
        for (int e = tid; e < E0; e += NT) {
            int uu = U[e], vv = V[e];
            if (uu == node) {
                int w = vv; unsigned m = 1u << (w & 31);
                unsigned old = atomicOr(&s_hb[w >> 5], m);
                if (!(old & m)) { int i = atomicAdd(&s_bc[2], 1); s_tmp[i] = w; s_vis[w] = 1; }
            }
            if (vv == node) {
                int w = uu; unsigned m = 1u << (w & 31);
                unsigned old = atomicOr(&s_hb[w >> 5], m);
                if (!(old & m)) { int i = atomicAdd(&s_bc[2], 1); s_tmp[i] = w; s_vis[w] = 1; }
            }
        }
        __syncthreads();
        // eager relabel Hn = H \ {node} (U/V frozen afterwards)
        for (int e = tid; e < E0; e += NT) {
            int uu = U[e];
            if (uu != node && ((s_hb[uu >> 5] >> (uu & 31)) & 1)) U[e] = node;
            int vv = V[e];
            if (vv != node && ((s_hb[vv >> 5] >> (vv & 31)) & 1)) V[e] = node;
        }
        __syncthreads();
    }

    // ---- symmetry append (only iteration ever needing it) ----
    // BM is pre-zeroed by the grid-parallel zeroBM kernel on the stream.
    for (int e = tid; e < E0; e += NT) {
        int uu = U[e], vv = V[e];
        if (uu != vv) {
            unsigned code = ((unsigned)uu << 12) | (unsigned)vv;
            atomicOr(&BM[code >> 5], 1u << (code & 31));
        }
    }
    __syncthreads();
    // single-pass ordered compaction: 32 arcs/thread bitmask + one block scan per 32K chunk
    for (int t0 = 0; t0 < E0; t0 += NT * 32) {
        unsigned fm = 0u;
        const int base = t0 + tid * 32;
        for (int j = 0; j < 32; ++j) {
            int e = base + j;
            if (e < E0) {
                int uu = U[e], vv = V[e];
                if (uu != vv) {
                    unsigned rc = ((unsigned)vv << 12) | (unsigned)uu;
                    unsigned old = atomicOr(&BM[rc >> 5], 0u);   // L2 read
                    if (!((old >> (rc & 31)) & 1u)) fm |= (1u << j);
                }
            }
        }
        int tot;
        int off = blockScanExcl(__popc(fm), s_w, &tot);
        int r = s_bc[5] + off;
        unsigned m = fm;
        while (m) {
            int j = __ffs((int)m) - 1; m &= m - 1;
            int e = base + j;
            U[E0 + r] = V[e]; V[E0 + r] = U[e];
            ++r;
        }
        __syncthreads();
        if (tid == 0) s_bc[5] += tot;
        __syncthreads();
    }
    const int E1 = E0 + s_bc[5];

    // ---- build static CSR, OUT-endpoint only ----
    for (int n = tid; n < NNODES; n += NT) s_roff[n] = 0;
    __syncthreads();
    for (int e = tid; e < E1; e += NT) {
        int uu = U[e], vv = V[e];
        if (uu != vv) atomicAdd(&s_roff[uu], 1);
    }
    __syncthreads();
    {
        int n0 = tid * 4;
        int c0 = s_roff[n0], c1 = s_roff[n0 + 1], c2 = s_roff[n0 + 2], c3 = s_roff[n0 + 3];
        int tot;
        int off = blockScanExcl(c0 + c1 + c2 + c3, s_w, &tot);
        int st = off;
        s_roff[n0] = st;     s_rend[n0] = st;     st += c0;
        s_roff[n0 + 1] = st; s_rend[n0 + 1] = st; st += c1;
        s_roff[n0 + 2] = st; s_rend[n0 + 2] = st; st += c2;
        s_roff[n0 + 3] = st; s_rend[n0 + 3] = st;
    }
    __syncthreads();
    for (int e = tid; e < E1; e += NT) {
        int uu = U[e], vv = V[e];
        if (uu != vv) {
            int p = atomicAdd(&s_rend[uu], 1);
            OTH[p] = vv;
        }
    }
    __syncthreads();
    {   // flush iter-0 staged H into global NBR
        const int cnt0 = s_bc[2];
        for (int i = tid; i < cnt0; i += NT) NBR[i] = s_tmp[i];
    }
    // ---- dump handoff state ----
    for (int i = tid; i < NNODES; i += NT) {
        int nd = (int)s_order[i];
        ORDV[i]  = nd | (s_vis[nd] ? 0x8000 : 0);
        ROFFG[i] = s_roff[i];
        RENDG[i] = s_rend[i];
    }
    if (tid == 0) { HAND[0] = E1; HAND[1] = s_bc[2]; HAND[2] = s_bc[0]; }
}

// ================= Phase A2: main loop, SINGLE WAVE, zero barriers =================
// QUAD-processing + fused meta word.
//   s_meta[node] = (order_slot(label) << 16) | (sel(label) ? 0x8000 : 0) | label
// One gather yields label w, slot(w) (for visited-mark) and sel(w) (relabel guard).
// Invariant holds because label targets are only {self} U {selected hubs}, hubs are
// immutable, and a hub's pre-selection meta is statically (slot<<16)|id -> selection
// is a plain store, relabel writes the wave-uniform (hubslot<<16)|hub|0x8000.
// Four hubs selected per snapshot; absorbed candidates (caught by watch ballots)
// are dropped, not replaced — order stays exact since inter-candidate slots were
// already visited at snapshot time.
__global__ __launch_bounds__(64, 1)
void phaseA2(const int* __restrict__ OTH, int* __restrict__ NBR,
             const int* __restrict__ ORDV, const int* __restrict__ ROFFG,
             const int* __restrict__ RENDG, const int* __restrict__ HAND,
             int* __restrict__ SEL, int* __restrict__ CNTS,
             int* __restrict__ NST, int* __restrict__ FIL, int* __restrict__ SC,
             int* __restrict__ LABG, int* __restrict__ RNKG)
{
    __shared__ unsigned short s_ord[NNODES];          // order slot -> node id
    __shared__ unsigned int   s_visbits[NNODES / 32]; // visited bit per ORDER SLOT
    __shared__ unsigned int   s_meta[NNODES];         // fused label/slot/sel word
    __shared__ unsigned short s_so[NNODES];           // selection order of hubs
    __shared__ int s_cnt[NNODES];                     // per-iteration |H_k|
    __shared__ int s_stamp[NNODES];                   // dedup epoch; reused as rank
    __shared__ int s_roff[NNODES];
    __shared__ int s_rend[NNODES];

    const int ln = threadIdx.x;                   // single wave: tid == lane
    const unsigned long long ltm = (1ull << ln) - 1ull;
    const int cnt0 = HAND[1], hub0 = HAND[2];

    for (int i = ln; i < NNODES / 32; i += 64) s_visbits[i] = 0u;
    for (int i = ln; i < NNODES; i += 64) {
        int ov = ORDV[i];
        int nd = ov & 0x7FFF;
        s_ord[i] = (unsigned short)nd;
        s_meta[nd] = ((unsigned)i << 16) | (unsigned)nd;   // slot | id, unselected
        s_roff[i] = ROFFG[i];
        s_rend[i] = RENDG[i];
        s_stamp[i] = 0; s_cnt[i] = 0;
        if (ov & 0x8000) atomicOr(&s_visbits[i >> 5], 1u << (i & 31));
    }
    if (ln == 0) {
        // hub0 is order-slot 0 (highest degree): meta = (0<<16)|hub0|selbit
        s_meta[hub0] = (unsigned)hub0 | 0x8000u;
        s_so[0] = (unsigned short)hub0;
        s_cnt[0] = cnt0;
    }
    // single wave: instruction order + lgkmcnt waits give LDS visibility; no barrier.

    int nc = cnt0;   // NBR cursor, wave-uniform register
    int k = 1;

    // register-resident bitmask extraction: lane ln holds words {ln, ln+64}
    unsigned lo = 0u, hi = 0u;
    auto reload = [&]() { lo = ~s_visbits[ln]; hi = ~s_visbits[ln + 64]; };
    auto extract = [&]() -> int {
        unsigned long long b = __ballot(lo != 0u);
        if (b) {
            int sl = __ffsll((long long)b) - 1;
            unsigned ww = __shfl(lo, sl, 64);
            if (ln == sl) lo &= lo - 1;
            return sl * 32 + (__ffs((int)ww) - 1);
        }
        b = __ballot(hi != 0u);
        if (b) {
            int sl = __ffsll((long long)b) - 1;
            unsigned ww = __shfl(hi, sl, 64);
            if (ln == sl) hi &= hi - 1;
            return 2048 + sl * 32 + (__ffs((int)ww) - 1);
        }
        return -1;
    };

    // process hub's row; returns watch-hit mask (bit0=wA, bit1=wB, bit2=wC)
    auto procRow = [&](int hub, int hslot, int rb, int re, int o0,
                       int wA, int wB, int wC) -> int {
        const unsigned relv = ((unsigned)hslot << 16) | (unsigned)hub | 0x8000u;
        const bool haveW = (wA >= 0) | (wB >= 0) | (wC >= 0);
        int hitm = 0;
        int o = o0;
        for (int s0 = rb; s0 < re; s0 += 64) {
            unsigned g = (o >= 0) ? s_meta[o] : 0u;      // ONE fused gather
            int w = (o >= 0) ? (int)(g & 0x7FFFu) : hub;
            bool cnd = (w != hub);
            int old = k;
            if (cnd) old = atomicMax(&s_stamp[w], k);
            bool nw = cnd && (old < k);
            unsigned long long bal = __ballot(nw);
            if (nw) {
                NBR[nc + __popcll(bal & ltm)] = w;       // fire-and-forget
                int slot = (int)(g >> 16);               // slot(w) from the gather
                atomicOr(&s_visbits[slot >> 5], 1u << (slot & 31));
                if (!(g & 0x8000u)) s_meta[w] = relv;    // relabel unselected w
            }
            nc += __popcll(bal);
            if (haveW) {
                bool aw = nw && (w == wA || w == wB || w == wC);
                if (__ballot(aw) != 0ull) {
                    if (__ballot(nw && w == wA)) hitm |= 1;
                    if (__ballot(nw && w == wB)) hitm |= 2;
                    if (__ballot(nw && w == wC)) hitm |= 4;
                }
            }
            int s1 = s0 + 64;                            // rare: out-degree > 64
            o = (s1 + ln < re) ? OTH[s1 + ln] : -1;
        }
        return hitm;
    };

    for (;;) {
        reload();
        int sl0 = extract();
        if (sl0 < 0) break;
        int sl1 = extract(), sl2 = -1, sl3 = -1;
        if (sl1 >= 0) { sl2 = extract(); if (sl2 >= 0) sl3 = extract(); }

        // node ids (4 independent LDS reads, pipelined)
        int c0 = (int)s_ord[sl0];
        int c1 = (sl1 >= 0) ? (int)s_ord[sl1] : -1;
        int c2 = (sl2 >= 0) ? (int)s_ord[sl2] : -1;
        int c3 = (sl3 >= 0) ? (int)s_ord[sl3] : -1;

        {   // pre-mark all candidates visited (lane-parallel, idempotent w.r.t. absorption)
            int ms = (ln == 0) ? sl0 : (ln == 1) ? sl1 : (ln == 2) ? sl2 : sl3;
            if (ln < 4 && ms >= 0) atomicOr(&s_visbits[ms >> 5], 1u << (ms & 31));
        }

        // all CSR rows + all OTH first-chunks issue together -> one shared L2 wait
        int rb0 = s_roff[c0], re0 = s_rend[c0];
        int rb1 = 0, re1 = 0, rb2 = 0, re2 = 0, rb3 = 0, re3 = 0;
        if (c1 >= 0) { rb1 = s_roff[c1]; re1 = s_rend[c1]; }
        if (c2 >= 0) { rb2 = s_roff[c2]; re2 = s_rend[c2]; }
        if (c3 >= 0) { rb3 = s_roff[c3]; re3 = s_rend[c3]; }
        int v0 = (rb0 + ln < re0) ? OTH[rb0 + ln] : -1;
        int v1 = (c1 >= 0 && rb1 + ln < re1) ? OTH[rb1 + ln] : -1;
        int v2 = (c2 >= 0 && rb2 + ln < re2) ? OTH[rb2 + ln] : -1;
        int v3 = (c3 >= 0 && rb3 + ln < re3) ? OTH[rb3 + ln] : -1;

        // ---- proc c0 ----
        if (ln == 0) {
            s_meta[c0] = ((unsigned)sl0 << 16) | (unsigned)c0 | 0x8000u;  // plain store, no RMW
            s_so[k] = (unsigned short)c0;
        }
        int begin = nc;
        int hit = procRow(c0, sl0, rb0, re0, v0, c1, c2, c3);
        if (ln == 0) s_cnt[k] = nc - begin;
        k++;
        if (hit & 1) c1 = -1;
        if (hit & 2) c2 = -1;
        if (hit & 4) c3 = -1;

        // ---- proc c1 ----
        if (c1 >= 0) {
            if (ln == 0) {
                s_meta[c1] = ((unsigned)sl1 << 16) | (unsigned)c1 | 0x8000u;
                s_so[k] = (unsigned short)c1;
            }
            begin = nc;
            hit = procRow(c1, sl1, rb1, re1, v1, c2, c3, -1);
            if (ln == 0) s_cnt[k] = nc - begin;
            k++;
            if (hit & 1) c2 = -1;
            if (hit & 2) c3 = -1;
        }
        // ---- proc c2 ----
        if (c2 >= 0) {
            if (ln == 0) {
                s_meta[c2] = ((unsigned)sl2 << 16) | (unsigned)c2 | 0x8000u;
                s_so[k] = (unsigned short)c2;
            }
            begin = nc;
            hit = procRow(c2, sl2, rb2, re2, v2, c3, -1, -1);
            if (ln == 0) s_cnt[k] = nc - begin;
            k++;
            if (hit & 1) c3 = -1;
        }
        // ---- proc c3 ----
        if (c3 >= 0) {
            if (ln == 0) {
                s_meta[c3] = ((unsigned)sl3 << 16) | (unsigned)c3 | 0x8000u;
                s_so[k] = (unsigned short)c3;
            }
            begin = nc;
            procRow(c3, sl3, rb3, re3, v3, -1, -1, -1);
            if (ln == 0) s_cnt[k] = nc - begin;
            k++;
        }
    }
    const int K = k;

    // ---- rank of selected nodes among sorted(select); store into s_stamp ----
    // n selected  <=>  meta low id == n AND selbit set
    {
        int base = 0;
        for (int c = 0; c < NNODES / 64; ++c) {
            int n = c * 64 + ln;
            unsigned mv = s_meta[n];
            int f = ((mv & 0x8000u) != 0u) && ((int)(mv & 0x7FFFu) == n);
            unsigned long long b = __ballot(f);
            s_stamp[n] = base + __popcll(b & ltm);
            base += __popcll(b);
        }
    }
    // ---- SEL / CNTS / NST (exclusive prefix of CNTS) ----
    {
        int nb = 0;
        for (int c = 0; c * 64 < K; ++c) {
            int i = c * 64 + ln;
            int cv = (i < K) ? s_cnt[i] : 0;
            int x = cv;
#pragma unroll
            for (int off = 1; off < 64; off <<= 1) {
                int t = __shfl_up(x, off, 64);
                if (ln >= off) x += t;
            }
            if (i < K) { NST[i] = nb + x - cv; CNTS[i] = cv; SEL[i] = (int)s_so[i]; }
            nb += __shfl(x, 63, 64);
        }
    }
    // ---- FIL forward-fill via ballot + clz ----
    {
        int carry = 0;
        for (int c = 0; c * 64 < K; ++c) {
            int i = c * 64 + ln;
            int f = (i < K) && (s_cnt[i] > 0);
            unsigned long long b = __ballot(f);
            unsigned long long m = b & ((ln == 63) ? ~0ull : ((1ull << (ln + 1)) - 1ull));
            int fil = m ? (c * 64 + 63 - __clzll(m)) : carry;
            if (i < K) FIL[i] = fil;
            carry = b ? (c * 64 + 63 - __clzll(b)) : carry;
        }
    }
    if (ln == 0) SC[0] = K;
    // ---- dump labels + ranks for A3 ----
    for (int i = ln; i < NNODES; i += 64) {
        LABG[i] = (int)(s_meta[i] & 0x7FFFu);
        RNKG[i] = s_stamp[i];
    }
}

// ================= Phase A3: final arc compaction + remap (NT=1024) =================
__global__ __launch_bounds__(NT, 1)
void phaseA3(const int* __restrict__ U, const int* __restrict__ V,
             const int* __restrict__ LABG, const int* __restrict__ RNKG,
             const int* __restrict__ HAND, int* __restrict__ SC,
             int* __restrict__ TMP, float* __restrict__ out)
{
    __shared__ unsigned short l_lab[NNODES];
    __shared__ int l_rnk[NNODES];
    __shared__ int s_w[16];
    __shared__ int s_base[1];

    const int tid = threadIdx.x;
    for (int i = tid; i < NNODES; i += NT) {
        l_lab[i] = (unsigned short)LABG[i];
        l_rnk[i] = RNKG[i];
    }
    if (tid == 0) s_base[0] = 0;
    __syncthreads();

    const int E1 = HAND[0];
    const int K  = SC[0];
    const size_t obase = (size_t)K * 8192;

    // single-pass ordered compaction: 64 arcs/thread bitmask + one block scan
    for (int t0 = 0; t0 < E1; t0 += NT * 64) {
        unsigned long long fm = 0ull;
        const int base = t0 + tid * 64;
        if (base + 64 <= E1) {                   // vectorized int4 loads
            const int4* U4 = (const int4*)(U + base);
            const int4* V4 = (const int4*)(V + base);
#pragma unroll
            for (int q = 0; q < 16; ++q) {
                int4 a = U4[q], b = V4[q];
                int j = q * 4;
                if ((int)l_lab[a.x] != (int)l_lab[b.x]) fm |= 1ull << j;
                if ((int)l_lab[a.y] != (int)l_lab[b.y]) fm |= 1ull << (j + 1);
                if ((int)l_lab[a.z] != (int)l_lab[b.z]) fm |= 1ull << (j + 2);
                if ((int)l_lab[a.w] != (int)l_lab[b.w]) fm |= 1ull << (j + 3);
            }
        } else {
            for (int j = 0; j < 64; ++j) {
                int e = base + j;
                if (e < E1) {
                    if ((int)l_lab[U[e]] != (int)l_lab[V[e]]) fm |= 1ull << j;
                }
            }
        }
        int tot;
        int off = blockScanExcl(__popcll(fm), s_w, &tot);
        int r = s_base[0] + off;
        unsigned long long m = fm;
        while (m) {
            int j = __ffsll((long long)m) - 1; m &= m - 1;
            int e = base + j;
            out[obase + (size_t)r] = (float)l_rnk[(int)l_lab[U[e]]];
            TMP[r] = l_rnk[(int)l_lab[V[e]]];
            ++r;
        }
        __syncthreads();
        if (tid == 0) s_base[0] += tot;
        __syncthreads();
    }
    const int Ef = s_base[0];
    if (tid == 0) SC[1] = Ef;
    for (int r = tid; r < Ef; r += NT)
        out[obase + (size_t)Ef + (size_t)r] = (float)TMP[r];
}

// ---------------- Phase B: END rows (Dv | mean) with fill indirection ----------------
__global__ __launch_bounds__(256, 4)
void phaseB(const float* __restrict__ x,
            const float* __restrict__ W1, const float* __restrict__ W2,
            const float* __restrict__ B1, const float* __restrict__ B2,
            const int* __restrict__ NBR, const int* __restrict__ SEL,
            const int* __restrict__ CNTS, const int* __restrict__ NST,
            const int* __restrict__ FIL, const int* __restrict__ SC,
            float* __restrict__ out)
{
    const int K = SC[0];
    const int k = blockIdx.x;
    if (k >= K) return;
    const int kk   = FIL[k];
    const int node = SEL[kk];
    const int cnt  = CNTS[kk];
    const int st   = NST[kk];
    const int tid  = threadIdx.x;
    const float4* x4 = (const float4*)x;

    float4 acc[4];
#pragma unroll
    for (int j = 0; j < 4; j++) acc[j] = make_float4(0.f, 0.f, 0.f, 0.f);

    for (int r = 0; r < cnt; ++r) {
        const float4* row = x4 + (size_t)NBR[st + r] * 1024;
#pragma unroll
        for (int j = 0; j < 4; j++) {
            float4 t = row[tid + j * 256];
            acc[j].x += t.x; acc[j].y += t.y; acc[j].z += t.z; acc[j].w += t.w;
        }
    }

    const float fc  = (float)cnt;
    const float inv = 1.0f / (float)(cnt > 1 ? cnt : 1);
    const float4* xr = x4 + (size_t)node * 1024;
    float4* o4 = (float4*)(out + (size_t)k * 8192);

#pragma unroll
    for (int j = 0; j < 4; j++) {
        int c = tid + j * 256;
        float4 w1 = ((const float4*)W1)[c], b1 = ((const float4*)B1)[c];
        float4 w2 = ((const float4*)W2)[c], b2 = ((const float4*)B2)[c];
        float4 xv = xr[c];
        float4 pd, pm;
        pd.x = xv.x * w2.x + b2.x;
        pd.y = xv.y * w2.y + b2.y;
        pd.z = xv.z * w2.z + b2.z;
        pd.w = xv.w * w2.w + b2.w;
        pm.x = (acc[j].x * w1.x + fc * b1.x) * inv;
        pm.y = (acc[j].y * w1.y + fc * b1.y) * inv;
        pm.z = (acc[j].z * w1.z + fc * b1.z) * inv;
        pm.w = (acc[j].w * w1.w + fc * b1.w) * inv;
        o4[c] = pd;
        o4[1024 + c] = pm;
    }
}

extern "C" void kernel_launch(void* const* d_in, const int* in_sizes, int n_in,
                              void* d_out, int out_size, void* d_ws, size_t ws_size,
                              hipStream_t stream)
{
    const float* x  = (const float*)d_in[0];
    const int*   ei = (const int*)d_in[1];
    const float* W1 = (const float*)d_in[2];
    const float* W2 = (const float*)d_in[3];
    const float* B1 = (const float*)d_in[4];
    const float* B2 = (const float*)d_in[5];
    const int E0 = in_sizes[1] / 2;

    char* w = (char*)d_ws;
    int* U = (int*)w;                         // [ECAP]
    int* V = U + ECAP;                        // [ECAP]
    unsigned int* BM = (unsigned int*)(V + ECAP);   // 2 MB bitmap (iter-0 only)
    int* OTH = (int*)BM;                      // [2*ECAP] static CSR other-endpoint
    int* NBR = OTH + 2 * ECAP;                // [2*ECAP]
    int* TMP = NBR + 2 * ECAP;                // [2*ECAP] A3 scratch
    char* meta = (char*)BM + (2u << 20);
    int* SEL   = (int*)meta;
    int* CNTS  = SEL  + NNODES;
    int* NST   = CNTS + NNODES;
    int* FIL   = NST  + NNODES;
    int* SC    = FIL  + NNODES;               // [16]
    int* ORDV  = SC   + 16;
    int* ROFFG = ORDV + NNODES;
    int* RENDG = ROFFG + NNODES;
    int* LABG  = RENDG + NNODES;
    int* RNKG  = LABG + NNODES;
    int* HAND  = RNKG + NNODES;               // [16]
    float* out = (float*)d_out;

    // grid-parallel zero of the 2MB BM bitmap (plain kernel; graph-capture-safe)
    hipLaunchKernelGGL(zeroBM, dim3(512), dim3(256), 0, stream, (int4*)BM);

    hipLaunchKernelGGL(phaseA1, dim3(1), dim3(NT), 0, stream,
                       ei, E0, U, V, BM, NBR, OTH, ORDV, ROFFG, RENDG, HAND);
    hipLaunchKernelGGL(phaseA2, dim3(1), dim3(64), 0, stream,
                       OTH, NBR, ORDV, ROFFG, RENDG, HAND,
                       SEL, CNTS, NST, FIL, SC, LABG, RNKG);
    hipLaunchKernelGGL(phaseA3, dim3(1), dim3(NT), 0, stream,
                       U, V, LABG, RNKG, HAND, SC, TMP, out);
    hipLaunchKernelGGL(phaseB, dim3(NNODES), dim3(256), 0, stream,
                       x, W1, W2, B1, B2, NBR, SEL, CNTS, NST, FIL, SC, out);
}

// Round 5
// 1004.859 us; speedup vs baseline: 1.1845x; 1.0420x over previous
//
#include <hip/hip_runtime.h>
#include <hip/hip_bf16.h>

#define NT 1024
#define NNODES 4096
#define ECAP 65536   // max arcs after iteration-1 symmetrization (E0 <= 32768)

// ---------------- grid-parallel 2MB bitmap zero (replaces hipMemsetAsync) ----------------
__global__ __launch_bounds__(256)
void zeroBM(int4* __restrict__ bm) {
    bm[(size_t)blockIdx.x * 256 + threadIdx.x] = make_int4(0, 0, 0, 0);
}

// ---------------- block-wide exclusive scan over NT=1024 values ----------------
__device__ __forceinline__ int blockScanExcl(int v, int* s_w, int* total) {
    const int tid  = threadIdx.x;
    const int lane = tid & 63;
    const int wv   = tid >> 6;
    int x = v;
#pragma unroll
    for (int off = 1; off < 64; off <<= 1) {
        int t = __shfl_up(x, off, 64);
        if (lane >= off) x += t;
    }
    if (lane == 63) s_w[wv] = x;
    __syncthreads();
    if (tid < 16) {
        int y = s_w[tid];
#pragma unroll
        for (int off = 1; off < 16; off <<= 1) {
            int t = __shfl_up(y, off, 16);
            if (tid >= off) y += t;
        }
        s_w[tid] = y;
    }
    __syncthreads();
    int base = wv ? s_w[wv - 1] : 0;
    int tot  = s_w[15];
    __syncthreads();   // protect s_w reuse
    *total = tot;
    return base + x - v;   // exclusive prefix
}

// ================= Phase A1: preamble (R4-exact), dump handoff state =================
// s_bc slots: 0=node 2=nbrCnt 4=orderBase 5=appendBase 7=maxdeg 9=not64
__global__ __launch_bounds__(NT, 1)
void phaseA1(const int* __restrict__ ei, int E0,
             int* __restrict__ U, int* __restrict__ V,
             unsigned int* __restrict__ BM,
             int* __restrict__ NBR, int* __restrict__ OTH,
             int* __restrict__ ORDV, int* __restrict__ ROFFG, int* __restrict__ RENDG,
             int* __restrict__ HAND)
{
    __shared__ unsigned short s_order[NNODES];
    __shared__ unsigned char  s_vis[NNODES];
    __shared__ unsigned char  s_rank[NNODES];     // counting-sort within-group rank
    __shared__ unsigned int   s_hb[NNODES / 32];
    __shared__ int s_roff[NNODES];
    __shared__ int s_rend[NNODES];
    __shared__ int s_tmp[NNODES];
    __shared__ int s_mat[64][65];                 // [deg][group] counts / prefixes; col 64 = desc base
    __shared__ int s_w[16];
    __shared__ int s_bc[16];

    const int tid = threadIdx.x;

    for (int i = tid; i < NNODES; i += NT) { s_vis[i] = 0; s_tmp[i] = 0; }
    for (int i = tid; i < NNODES / 32; i += NT) s_hb[i] = 0;
    if (tid < 16) s_bc[tid] = 0;
    __syncthreads();

    // ---- detect int64 vs int32 edge buffer ----
    for (int i = tid; i < E0; i += NT)
        if (ei[2 * i + 1] != 0) s_bc[9] = 1;
    __syncthreads();
    const int is64 = !s_bc[9];

    // ---- copy edges + degree histogram (I+O) ----
    for (int e = tid; e < E0; e += NT) {
        int uu = ei[is64 ? 2 * e : e];
        int vv = ei[is64 ? 2 * (E0 + e) : (E0 + e)];
        U[e] = uu; V[e] = vv;
        atomicAdd(&s_tmp[uu], 1);
        atomicAdd(&s_tmp[vv], 1);
    }
    __syncthreads();
    for (int n = tid; n < NNODES; n += NT) atomicMax(&s_bc[7], s_tmp[n]);
    __syncthreads();
    const int maxd = s_bc[7];

    // ---- stable argsort by descending degree ----
    if (maxd < 64) {
        // fast path: stable counting sort, ~5 barriers total.
        const int wv = tid >> 6, lane = tid & 63;
        const unsigned long long ltm = (1ull << lane) - 1ull;
        for (int g = wv; g < 64; g += 16) {
            int n = g * 64 + lane;
            int d = s_tmp[n];
            int rk = 0;
            for (int dd = 0; dd < 64; ++dd) {
                unsigned long long bal = __ballot(d == dd);
                if (lane == 0) s_mat[dd][g] = __popcll(bal);
                if (d == dd) rk = __popcll(bal & ltm);
            }
            s_rank[n] = (unsigned char)rk;
        }
        __syncthreads();
        if (tid < 64) {                      // per-degree prefix across the 64 id-groups
            int run = 0;
            for (int g = 0; g < 64; ++g) { int t = s_mat[tid][g]; s_mat[tid][g] = run; run += t; }
            s_mat[tid][64] = run;            // total per degree
        }
        __syncthreads();
        if (tid < 64) {                      // descending-degree exclusive base
            int x = s_mat[tid][64];
#pragma unroll
            for (int off = 1; off < 64; off <<= 1) {
                int t = __shfl_up(x, off, 64);
                if (tid >= off) x += t;
            }
            int T = __shfl(x, 63, 64);
            s_mat[tid][64] = T - x;          // sum of bins with degree > tid
        }
        __syncthreads();
        for (int g = wv; g < 64; g += 16) {
            int n = g * 64 + lane;
            int d = s_tmp[n];
            int pos = s_mat[d][64] + s_mat[d][g] + (int)s_rank[n];
            s_order[pos] = (unsigned short)n;
        }
        __syncthreads();
    } else {
        // legacy fallback (exact, slow): one scan round per degree value
        for (int d = maxd; d >= 0; --d) {
            int n0 = tid * 4;
            int f0 = (s_tmp[n0] == d), f1 = (s_tmp[n0 + 1] == d);
            int f2 = (s_tmp[n0 + 2] == d), f3 = (s_tmp[n0 + 3] == d);
            int tot;
            int off = blockScanExcl(f0 + f1 + f2 + f3, s_w, &tot);
            int idx = s_bc[4] + off;
            if (f0) s_order[idx++] = (unsigned short)n0;
            if (f1) s_order[idx++] = (unsigned short)(n0 + 1);
            if (f2) s_order[idx++] = (unsigned short)(n0 + 2);
            if (f3) s_order[idx++] = (unsigned short)(n0 + 3);
            __syncthreads();
            if (tid == 0) s_bc[4] += tot;
            __syncthreads();
        }
    }

    // ---- iteration 0 (full-array scans, eager relabel) ----
    if (tid == 0) {
        int nd = s_order[0];
        s_bc[0] = nd; s_vis[nd] = 1;
    }
    __syncthreads();
    {
        const int node = s_bc[0];
        for (int e = tid; e < E0; e += NT) {
            int uu = U[e], vv = V[e];
            if (uu == node) {
                int w = vv; unsigned m = 1u << (w & 31);
                unsigned old = atomicOr(&s_hb[w >> 5], m);
                if (!(old & m)) { int i = atomicAdd(&s_bc[2], 1); s_tmp[i] = w; s_vis[w] = 1; }
            }
            if (vv == node) {
                int w = uu; unsigned m = 1u << (w & 31);
                unsigned old = atomicOr(&s_hb[w >> 5], m);
                if (!(old & m)) { int i = atomicAdd(&s_bc[2], 1); s_tmp[i] = w; s_vis[w] = 1; }
            }
        }
        __syncthreads();
        // eager relabel Hn = H \ {node} (U/V frozen afterwards)
        for (int e = tid; e < E0; e += NT) {
            int uu = U[e];
            if (uu != node && ((s_hb[uu >> 5] >> (uu & 31)) & 1)) U[e] = node;
            int vv = V[e];
            if (vv != node && ((s_hb[vv >> 5] >> (vv & 31)) & 1)) V[e] = node;
        }
        __syncthreads();
    }

    // ---- symmetry append (only iteration ever needing it) ----
    // BM is pre-zeroed by the grid-parallel zeroBM kernel on the stream.
    for (int e = tid; e < E0; e += NT) {
        int uu = U[e], vv = V[e];
        if (uu != vv) {
            unsigned code = ((unsigned)uu << 12) | (unsigned)vv;
            atomicOr(&BM[code >> 5], 1u << (code & 31));
        }
    }
    __syncthreads();
    // single-pass ordered compaction: 32 arcs/thread bitmask + one block scan per 32K chunk
    for (int t0 = 0; t0 < E0; t0 += NT * 32) {
        unsigned fm = 0u;
        const int base = t0 + tid * 32;
        for (int j = 0; j < 32; ++j) {
            int e = base + j;
            if (e < E0) {
                int uu = U[e], vv = V[e];
                if (uu != vv) {
                    unsigned rc = ((unsigned)vv << 12) | (unsigned)uu;
                    unsigned old = atomicOr(&BM[rc >> 5], 0u);   // L2 read
                    if (!((old >> (rc & 31)) & 1u)) fm |= (1u << j);
                }
            }
        }
        int tot;
        int off = blockScanExcl(__popc(fm), s_w, &tot);
        int r = s_bc[5] + off;
        unsigned m = fm;
        while (m) {
            int j = __ffs((int)m) - 1; m &= m - 1;
            int e = base + j;
            U[E0 + r] = V[e]; V[E0 + r] = U[e];
            ++r;
        }
        __syncthreads();
        if (tid == 0) s_bc[5] += tot;
        __syncthreads();
    }
    const int E1 = E0 + s_bc[5];

    // ---- build static CSR, OUT-endpoint only ----
    for (int n = tid; n < NNODES; n += NT) s_roff[n] = 0;
    __syncthreads();
    for (int e = tid; e < E1; e += NT) {
        int uu = U[e], vv = V[e];
        if (uu != vv) atomicAdd(&s_roff[uu], 1);
    }
    __syncthreads();
    {
        int n0 = tid * 4;
        int c0 = s_roff[n0], c1 = s_roff[n0 + 1], c2 = s_roff[n0 + 2], c3 = s_roff[n0 + 3];
        int tot;
        int off = blockScanExcl(c0 + c1 + c2 + c3, s_w, &tot);
        int st = off;
        s_roff[n0] = st;     s_rend[n0] = st;     st += c0;
        s_roff[n0 + 1] = st; s_rend[n0 + 1] = st; st += c1;
        s_roff[n0 + 2] = st; s_rend[n0 + 2] = st; st += c2;
        s_roff[n0 + 3] = st; s_rend[n0 + 3] = st;
    }
    __syncthreads();
    for (int e = tid; e < E1; e += NT) {
        int uu = U[e], vv = V[e];
        if (uu != vv) {
            int p = atomicAdd(&s_rend[uu], 1);
            OTH[p] = vv;
        }
    }
    __syncthreads();
    {   // flush iter-0 staged H into global NBR
        const int cnt0 = s_bc[2];
        for (int i = tid; i < cnt0; i += NT) NBR[i] = s_tmp[i];
    }
    // ---- dump handoff state ----
    for (int i = tid; i < NNODES; i += NT) {
        int nd = (int)s_order[i];
        ORDV[i]  = nd | (s_vis[nd] ? 0x8000 : 0);
        ROFFG[i] = s_roff[i];
        RENDG[i] = s_rend[i];
    }
    if (tid == 0) { HAND[0] = E1; HAND[1] = s_bc[2]; HAND[2] = s_bc[0]; }
}

// ================= Phase A2: main loop, SINGLE WAVE, zero barriers =================
// QUAD-processing + fused meta word + plain-store dedup.
//   s_meta[node] = (order_slot(label) << 16) | (sel(label) ? 0x8000 : 0) | label
// Dedup per hub k:
//   fast path (row fits one 64-chunk, ~99.98% of rows): every valid lane
//   volatile-stores its lane id to s_stamp[w] and reads back; unique hardware
//   winner per address -> owner iff readback == own lane id. No RMW in chain.
//   slow path (rare >64 rows): epoch atomicMax with key k<<6 (fast-path lane-id
//   residues < 64 <= k<<6 can never alias an epoch).
// Absorption of a later quad-candidate ci by an earlier proc is detected by ONE
// wave-uniform read: (s_meta[ci] & 0x7FFF) != ci  (absorbed <=> relabeled),
// issued together with ci's row gather -> no per-chunk watch ballots.
__global__ __launch_bounds__(64, 1)
void phaseA2(const int* __restrict__ OTH, int* __restrict__ NBR,
             const int* __restrict__ ORDV, const int* __restrict__ ROFFG,
             const int* __restrict__ RENDG, const int* __restrict__ HAND,
             int* __restrict__ SEL, int* __restrict__ CNTS,
             int* __restrict__ NST, int* __restrict__ FIL, int* __restrict__ SC,
             int* __restrict__ LABG, int* __restrict__ RNKG)
{
    __shared__ unsigned short s_ord[NNODES];          // order slot -> node id
    __shared__ unsigned int   s_visbits[NNODES / 32]; // visited bit per ORDER SLOT
    __shared__ unsigned int   s_meta[NNODES];         // fused label/slot/sel word
    __shared__ unsigned short s_so[NNODES];           // selection order of hubs
    __shared__ int s_cnt[NNODES];                     // per-iteration |H_k|
    __shared__ int s_stamp[NNODES];                   // dedup scratch; reused as rank
    __shared__ int s_roff[NNODES];
    __shared__ int s_rend[NNODES];

    const int ln = threadIdx.x;                   // single wave: tid == lane
    const unsigned long long ltm = (1ull << ln) - 1ull;
    const int cnt0 = HAND[1], hub0 = HAND[2];
    volatile int* vstamp = s_stamp;               // blocks store->load forwarding

    for (int i = ln; i < NNODES / 32; i += 64) s_visbits[i] = 0u;
    for (int i = ln; i < NNODES; i += 64) {
        int ov = ORDV[i];
        int nd = ov & 0x7FFF;
        s_ord[i] = (unsigned short)nd;
        s_meta[nd] = ((unsigned)i << 16) | (unsigned)nd;   // slot | id, unselected
        s_roff[i] = ROFFG[i];
        s_rend[i] = RENDG[i];
        s_stamp[i] = 0; s_cnt[i] = 0;
        if (ov & 0x8000) atomicOr(&s_visbits[i >> 5], 1u << (i & 31));
    }
    if (ln == 0) {
        // hub0 is order-slot 0 (highest degree): meta = (0<<16)|hub0|selbit
        s_meta[hub0] = (unsigned)hub0 | 0x8000u;
        s_so[0] = (unsigned short)hub0;
        s_cnt[0] = cnt0;
    }
    // single wave: instruction order + lgkmcnt waits give LDS visibility; no barrier.

    int nc = cnt0;   // NBR cursor, wave-uniform register
    int k = 1;

    // register-resident bitmask extraction: lane ln holds words {ln, ln+64}
    unsigned lo = 0u, hi = 0u;
    auto reload = [&]() { lo = ~s_visbits[ln]; hi = ~s_visbits[ln + 64]; };
    auto extract = [&]() -> int {
        unsigned long long b = __ballot(lo != 0u);
        if (b) {
            int sl = __ffsll((long long)b) - 1;
            unsigned ww = __shfl(lo, sl, 64);
            if (ln == sl) lo &= lo - 1;
            return sl * 32 + (__ffs((int)ww) - 1);
        }
        b = __ballot(hi != 0u);
        if (b) {
            int sl = __ffsll((long long)b) - 1;
            unsigned ww = __shfl(hi, sl, 64);
            if (ln == sl) hi &= hi - 1;
            return 2048 + sl * 32 + (__ffs((int)ww) - 1);
        }
        return -1;
    };

    // common commit for newly-found H members (bal already computed)
    auto commitNew = [&](unsigned g, int w, bool nw, unsigned long long bal,
                         unsigned relv) {
        if (nw) {
            NBR[nc + __popcll(bal & ltm)] = w;       // fire-and-forget
            int slot = (int)(g >> 16);               // slot(w) from the gather
            atomicOr(&s_visbits[slot >> 5], 1u << (slot & 31));
            if (!(g & 0x8000u)) s_meta[w] = relv;    // relabel unselected w
        }
        nc += __popcll(bal);
    };

    // fast proc: single chunk (re-rb <= 64), g pre-gathered for lane's o
    auto procFast = [&](int hub, int hslot, int o, unsigned g) {
        const unsigned relv = ((unsigned)hslot << 16) | (unsigned)hub | 0x8000u;
        int w = (o >= 0) ? (int)(g & 0x7FFFu) : hub;
        bool valid = (o >= 0) && (w != hub);
        if (valid) vstamp[w] = ln;                   // plain store (one winner/addr)
        int r = valid ? vstamp[w] : -1;              // in-order LDS read-back
        bool nw = valid && (r == ln);
        unsigned long long bal = __ballot(nw);
        commitNew(g, w, nw, bal, relv);
    };

    // slow proc: multi-chunk row, epoch atomicMax dedup with key k<<6
    auto procSlow = [&](int hub, int hslot, int rb, int re, int o0) {
        const unsigned relv = ((unsigned)hslot << 16) | (unsigned)hub | 0x8000u;
        const int key = k << 6;
        int o = o0;
        for (int s0 = rb; s0 < re; s0 += 64) {
            unsigned g = (o >= 0) ? s_meta[o] : 0u;
            int w = (o >= 0) ? (int)(g & 0x7FFFu) : hub;
            bool cnd = (w != hub);
            int old = key;
            if (cnd) old = atomicMax(&s_stamp[w], key);
            bool nw = cnd && (old < key);
            unsigned long long bal = __ballot(nw);
            commitNew(g, w, nw, bal, relv);
            int s1 = s0 + 64;
            o = (s1 + ln < re) ? OTH[s1 + ln] : -1;
        }
    };

    for (;;) {
        reload();
        int sl0 = extract();
        if (sl0 < 0) break;
        int sl1 = extract(), sl2 = -1, sl3 = -1;
        if (sl1 >= 0) { sl2 = extract(); if (sl2 >= 0) sl3 = extract(); }

        // node ids (4 independent LDS reads, pipelined)
        int c0 = (int)s_ord[sl0];
        int c1 = (sl1 >= 0) ? (int)s_ord[sl1] : -1;
        int c2 = (sl2 >= 0) ? (int)s_ord[sl2] : -1;
        int c3 = (sl3 >= 0) ? (int)s_ord[sl3] : -1;

        {   // pre-mark all candidates visited (lane-parallel, idempotent w.r.t. absorption)
            int ms = (ln == 0) ? sl0 : (ln == 1) ? sl1 : (ln == 2) ? sl2 : sl3;
            if (ln < 4 && ms >= 0) atomicOr(&s_visbits[ms >> 5], 1u << (ms & 31));
        }

        // all CSR rows + all OTH first-chunks issue together -> one shared L2 wait
        int rb0 = s_roff[c0], re0 = s_rend[c0];
        int rb1 = 0, re1 = 0, rb2 = 0, re2 = 0, rb3 = 0, re3 = 0;
        if (c1 >= 0) { rb1 = s_roff[c1]; re1 = s_rend[c1]; }
        if (c2 >= 0) { rb2 = s_roff[c2]; re2 = s_rend[c2]; }
        if (c3 >= 0) { rb3 = s_roff[c3]; re3 = s_rend[c3]; }
        int v0 = (rb0 + ln < re0) ? OTH[rb0 + ln] : -1;
        int v1 = (c1 >= 0 && rb1 + ln < re1) ? OTH[rb1 + ln] : -1;
        int v2 = (c2 >= 0 && rb2 + ln < re2) ? OTH[rb2 + ln] : -1;
        int v3 = (c3 >= 0 && rb3 + ln < re3) ? OTH[rb3 + ln] : -1;

        // ---- proc c0 (never absorbed: candidates were unvisited at snapshot) ----
        if (ln == 0) {
            s_meta[c0] = ((unsigned)sl0 << 16) | (unsigned)c0 | 0x8000u;  // plain store
            s_so[k] = (unsigned short)c0;
        }
        {
            unsigned g0 = (v0 >= 0) ? s_meta[v0] : 0u;
            int begin = nc;
            if (re0 - rb0 <= 64) procFast(c0, sl0, v0, g0);
            else                 procSlow(c0, sl0, rb0, re0, v0);
            if (ln == 0) s_cnt[k] = nc - begin;
            k++;
        }
        // ---- proc c1..c3: absorption check fused with row gather ----
        if (c1 >= 0) {
            unsigned m1 = s_meta[c1];                      // absorbed?
            unsigned g1 = (v1 >= 0) ? s_meta[v1] : 0u;     // row gather (parallel issue)
            if ((int)(m1 & 0x7FFFu) == c1) {
                if (ln == 0) {
                    s_meta[c1] = ((unsigned)sl1 << 16) | (unsigned)c1 | 0x8000u;
                    s_so[k] = (unsigned short)c1;
                }
                int begin = nc;
                if (re1 - rb1 <= 64) procFast(c1, sl1, v1, g1);
                else                 procSlow(c1, sl1, rb1, re1, v1);
                if (ln == 0) s_cnt[k] = nc - begin;
                k++;
            }
        }
        if (c2 >= 0) {
            unsigned m2 = s_meta[c2];
            unsigned g2 = (v2 >= 0) ? s_meta[v2] : 0u;
            if ((int)(m2 & 0x7FFFu) == c2) {
                if (ln == 0) {
                    s_meta[c2] = ((unsigned)sl2 << 16) | (unsigned)c2 | 0x8000u;
                    s_so[k] = (unsigned short)c2;
                }
                int begin = nc;
                if (re2 - rb2 <= 64) procFast(c2, sl2, v2, g2);
                else                 procSlow(c2, sl2, rb2, re2, v2);
                if (ln == 0) s_cnt[k] = nc - begin;
                k++;
            }
        }
        if (c3 >= 0) {
            unsigned m3 = s_meta[c3];
            unsigned g3 = (v3 >= 0) ? s_meta[v3] : 0u;
            if ((int)(m3 & 0x7FFFu) == c3) {
                if (ln == 0) {
                    s_meta[c3] = ((unsigned)sl3 << 16) | (unsigned)c3 | 0x8000u;
                    s_so[k] = (unsigned short)c3;
                }
                int begin = nc;
                if (re3 - rb3 <= 64) procFast(c3, sl3, v3, g3);
                else                 procSlow(c3, sl3, rb3, re3, v3);
                if (ln == 0) s_cnt[k] = nc - begin;
                k++;
            }
        }
    }
    const int K = k;

    // ---- rank of selected nodes among sorted(select); store into s_stamp ----
    // n selected  <=>  meta low id == n AND selbit set
    {
        int base = 0;
        for (int c = 0; c < NNODES / 64; ++c) {
            int n = c * 64 + ln;
            unsigned mv = s_meta[n];
            int f = ((mv & 0x8000u) != 0u) && ((int)(mv & 0x7FFFu) == n);
            unsigned long long b = __ballot(f);
            s_stamp[n] = base + __popcll(b & ltm);
            base += __popcll(b);
        }
    }
    // ---- SEL / CNTS / NST (exclusive prefix of CNTS) ----
    {
        int nb = 0;
        for (int c = 0; c * 64 < K; ++c) {
            int i = c * 64 + ln;
            int cv = (i < K) ? s_cnt[i] : 0;
            int x = cv;
#pragma unroll
            for (int off = 1; off < 64; off <<= 1) {
                int t = __shfl_up(x, off, 64);
                if (ln >= off) x += t;
            }
            if (i < K) { NST[i] = nb + x - cv; CNTS[i] = cv; SEL[i] = (int)s_so[i]; }
            nb += __shfl(x, 63, 64);
        }
    }
    // ---- FIL forward-fill via ballot + clz ----
    {
        int carry = 0;
        for (int c = 0; c * 64 < K; ++c) {
            int i = c * 64 + ln;
            int f = (i < K) && (s_cnt[i] > 0);
            unsigned long long b = __ballot(f);
            unsigned long long m = b & ((ln == 63) ? ~0ull : ((1ull << (ln + 1)) - 1ull));
            int fil = m ? (c * 64 + 63 - __clzll(m)) : carry;
            if (i < K) FIL[i] = fil;
            carry = b ? (c * 64 + 63 - __clzll(b)) : carry;
        }
    }
    if (ln == 0) SC[0] = K;
    // ---- dump labels + ranks for A3 ----
    for (int i = ln; i < NNODES; i += 64) {
        LABG[i] = (int)(s_meta[i] & 0x7FFFu);
        RNKG[i] = s_stamp[i];
    }
}

// ================= Phase A3: final arc compaction + remap (NT=1024) =================
__global__ __launch_bounds__(NT, 1)
void phaseA3(const int* __restrict__ U, const int* __restrict__ V,
             const int* __restrict__ LABG, const int* __restrict__ RNKG,
             const int* __restrict__ HAND, int* __restrict__ SC,
             int* __restrict__ TMP, float* __restrict__ out)
{
    __shared__ unsigned short l_lab[NNODES];
    __shared__ int l_rnk[NNODES];
    __shared__ int s_w[16];
    __shared__ int s_base[1];

    const int tid = threadIdx.x;
    for (int i = tid; i < NNODES; i += NT) {
        l_lab[i] = (unsigned short)LABG[i];
        l_rnk[i] = RNKG[i];
    }
    if (tid == 0) s_base[0] = 0;
    __syncthreads();

    const int E1 = HAND[0];
    const int K  = SC[0];
    const size_t obase = (size_t)K * 8192;

    // single-pass ordered compaction: 64 arcs/thread bitmask + one block scan
    for (int t0 = 0; t0 < E1; t0 += NT * 64) {
        unsigned long long fm = 0ull;
        const int base = t0 + tid * 64;
        if (base + 64 <= E1) {                   // vectorized int4 loads
            const int4* U4 = (const int4*)(U + base);
            const int4* V4 = (const int4*)(V + base);
#pragma unroll
            for (int q = 0; q < 16; ++q) {
                int4 a = U4[q], b = V4[q];
                int j = q * 4;
                if ((int)l_lab[a.x] != (int)l_lab[b.x]) fm |= 1ull << j;
                if ((int)l_lab[a.y] != (int)l_lab[b.y]) fm |= 1ull << (j + 1);
                if ((int)l_lab[a.z] != (int)l_lab[b.z]) fm |= 1ull << (j + 2);
                if ((int)l_lab[a.w] != (int)l_lab[b.w]) fm |= 1ull << (j + 3);
            }
        } else {
            for (int j = 0; j < 64; ++j) {
                int e = base + j;
                if (e < E1) {
                    if ((int)l_lab[U[e]] != (int)l_lab[V[e]]) fm |= 1ull << j;
                }
            }
        }
        int tot;
        int off = blockScanExcl(__popcll(fm), s_w, &tot);
        int r = s_base[0] + off;
        unsigned long long m = fm;
        while (m) {
            int j = __ffsll((long long)m) - 1; m &= m - 1;
            int e = base + j;
            out[obase + (size_t)r] = (float)l_rnk[(int)l_lab[U[e]]];
            TMP[r] = l_rnk[(int)l_lab[V[e]]];
            ++r;
        }
        __syncthreads();
        if (tid == 0) s_base[0] += tot;
        __syncthreads();
    }
    const int Ef = s_base[0];
    if (tid == 0) SC[1] = Ef;
    for (int r = tid; r < Ef; r += NT)
        out[obase + (size_t)Ef + (size_t)r] = (float)TMP[r];
}

// ---------------- Phase B: END rows (Dv | mean) with fill indirection ----------------
__global__ __launch_bounds__(256, 4)
void phaseB(const float* __restrict__ x,
            const float* __restrict__ W1, const float* __restrict__ W2,
            const float* __restrict__ B1, const float* __restrict__ B2,
            const int* __restrict__ NBR, const int* __restrict__ SEL,
            const int* __restrict__ CNTS, const int* __restrict__ NST,
            const int* __restrict__ FIL, const int* __restrict__ SC,
            float* __restrict__ out)
{
    const int K = SC[0];
    const int k = blockIdx.x;
    if (k >= K) return;
    const int kk   = FIL[k];
    const int node = SEL[kk];
    const int cnt  = CNTS[kk];
    const int st   = NST[kk];
    const int tid  = threadIdx.x;
    const float4* x4 = (const float4*)x;

    float4 acc[4];
#pragma unroll
    for (int j = 0; j < 4; j++) acc[j] = make_float4(0.f, 0.f, 0.f, 0.f);

    for (int r = 0; r < cnt; ++r) {
        const float4* row = x4 + (size_t)NBR[st + r] * 1024;
#pragma unroll
        for (int j = 0; j < 4; j++) {
            float4 t = row[tid + j * 256];
            acc[j].x += t.x; acc[j].y += t.y; acc[j].z += t.z; acc[j].w += t.w;
        }
    }

    const float fc  = (float)cnt;
    const float inv = 1.0f / (float)(cnt > 1 ? cnt : 1);
    const float4* xr = x4 + (size_t)node * 1024;
    float4* o4 = (float4*)(out + (size_t)k * 8192);

#pragma unroll
    for (int j = 0; j < 4; j++) {
        int c = tid + j * 256;
        float4 w1 = ((const float4*)W1)[c], b1 = ((const float4*)B1)[c];
        float4 w2 = ((const float4*)W2)[c], b2 = ((const float4*)B2)[c];
        float4 xv = xr[c];
        float4 pd, pm;
        pd.x = xv.x * w2.x + b2.x;
        pd.y = xv.y * w2.y + b2.y;
        pd.z = xv.z * w2.z + b2.z;
        pd.w = xv.w * w2.w + b2.w;
        pm.x = (acc[j].x * w1.x + fc * b1.x) * inv;
        pm.y = (acc[j].y * w1.y + fc * b1.y) * inv;
        pm.z = (acc[j].z * w1.z + fc * b1.z) * inv;
        pm.w = (acc[j].w * w1.w + fc * b1.w) * inv;
        o4[c] = pd;
        o4[1024 + c] = pm;
    }
}

extern "C" void kernel_launch(void* const* d_in, const int* in_sizes, int n_in,
                              void* d_out, int out_size, void* d_ws, size_t ws_size,
                              hipStream_t stream)
{
    const float* x  = (const float*)d_in[0];
    const int*   ei = (const int*)d_in[1];
    const float* W1 = (const float*)d_in[2];
    const float* W2 = (const float*)d_in[3];
    const float* B1 = (const float*)d_in[4];
    const float* B2 = (const float*)d_in[5];
    const int E0 = in_sizes[1] / 2;

    char* w = (char*)d_ws;
    int* U = (int*)w;                         // [ECAP]
    int* V = U + ECAP;                        // [ECAP]
    unsigned int* BM = (unsigned int*)(V + ECAP);   // 2 MB bitmap (iter-0 only)
    int* OTH = (int*)BM;                      // [2*ECAP] static CSR other-endpoint
    int* NBR = OTH + 2 * ECAP;                // [2*ECAP]
    int* TMP = NBR + 2 * ECAP;                // [2*ECAP] A3 scratch
    char* meta = (char*)BM + (2u << 20);
    int* SEL   = (int*)meta;
    int* CNTS  = SEL  + NNODES;
    int* NST   = CNTS + NNODES;
    int* FIL   = NST  + NNODES;
    int* SC    = FIL  + NNODES;               // [16]
    int* ORDV  = SC   + 16;
    int* ROFFG = ORDV + NNODES;
    int* RENDG = ROFFG + NNODES;
    int* LABG  = RENDG + NNODES;
    int* RNKG  = LABG + NNODES;
    int* HAND  = RNKG + NNODES;               // [16]
    float* out = (float*)d_out;

    // grid-parallel zero of the 2MB BM bitmap (plain kernel; graph-capture-safe)
    hipLaunchKernelGGL(zeroBM, dim3(512), dim3(256), 0, stream, (int4*)BM);

    hipLaunchKernelGGL(phaseA1, dim3(1), dim3(NT), 0, stream,
                       ei, E0, U, V, BM, NBR, OTH, ORDV, ROFFG, RENDG, HAND);
    hipLaunchKernelGGL(phaseA2, dim3(1), dim3(64), 0, stream,
                       OTH, NBR, ORDV, ROFFG, RENDG, HAND,
                       SEL, CNTS, NST, FIL, SC, LABG, RNKG);
    hipLaunchKernelGGL(phaseA3, dim3(1), dim3(NT), 0, stream,
                       U, V, LABG, RNKG, HAND, SC, TMP, out);
    hipLaunchKernelGGL(phaseB, dim3(NNODES), dim3(256), 0, stream,
                       x, W1, W2, B1, B2, NBR, SEL, CNTS, NST, FIL, SC, out);
}